// Round 3
// baseline (414.570 us; speedup 1.0000x reference)
//
#include <hip/hip_runtime.h>
#include <hip/hip_bf16.h>

typedef unsigned short u16;
typedef short s16x8 __attribute__((ext_vector_type(8)));
typedef float f32x4 __attribute__((ext_vector_type(4)));

#define MFMA_BF16(a, b, c) __builtin_amdgcn_mfma_f32_16x16x32_bf16((a), (b), (c), 0, 0, 0)

static constexpr int D_IN   = 64;
static constexpr int H_DIM  = 512;
static constexpr int M_TILE = 32;
static constexpr int AST    = 520;  // LDS row stride (bf16)
static constexpr int XST    = 72;   // LDS row stride for x tile

__device__ __forceinline__ u16 f2bf(float f) {
  unsigned u = __builtin_bit_cast(unsigned, f);
  u += 0x7fffu + ((u >> 16) & 1u);   // RNE
  return (u16)(u >> 16);
}
__device__ __forceinline__ float bfb2f(unsigned bits16) {
  return __builtin_bit_cast(float, bits16 << 16);
}
__device__ __forceinline__ float fast_tanh(float x) {
  float e = __expf(2.0f * x);
  return 1.0f - 2.0f * __builtin_amdgcn_rcpf(e + 1.0f);
}

// ---- prep: fp32 weights -> bf16, packed in MFMA-B-fragment order ----
// For each (ntg = 16-col tile, kc = 32-wide K chunk): 512 elems stored as
// lane*8 contiguous, lane=(q*16+ln), elem j -> B[k=kc*32+q*8+j][n=ntg*16+ln].
// ws layout (bf16): p0f[64x512] p0b[512x64] p1f p1b p2f p2b  (~2.2MB)
__global__ void prep_weights(const float* __restrict__ W0,
                             const float* __restrict__ W1,
                             const float* __restrict__ W2,
                             u16* __restrict__ ws) {
  u16* p0f = ws;                       // fwd W0: K=64,  N=512
  u16* p0b = p0f + D_IN * H_DIM;       // bwd W0^T: K=512, N=64
  u16* p1f = p0b + D_IN * H_DIM;
  u16* p1b = p1f + H_DIM * H_DIM;
  u16* p2f = p1b + H_DIM * H_DIM;
  u16* p2b = p2f + H_DIM * H_DIM;

  int t = blockIdx.x * 256 + threadIdx.x;   // 32768 threads total
  int lane = t & 63;
  int kc   = (t >> 6) & 15;
  int ntg  = t >> 10;                       // 0..31
  int ln = lane & 15, q = lane >> 4;
  int n = ntg * 16 + ln;
  int k = kc * 32 + q * 8;

  #pragma unroll
  for (int j = 0; j < 8; ++j) {
    p1f[t * 8 + j] = f2bf(W1[(k + j) * 512 + n]);
    p2f[t * 8 + j] = f2bf(W2[(k + j) * 512 + n]);
    p1b[t * 8 + j] = f2bf(W1[n * 512 + (k + j)]);
    p2b[t * 8 + j] = f2bf(W2[n * 512 + (k + j)]);
  }
  if (kc < 2) {  // W0 fwd: K=64 -> kc in {0,1}, ntg 0..31
    int t0 = (ntg * 2 + kc) * 64 + lane;
    #pragma unroll
    for (int j = 0; j < 8; ++j)
      p0f[t0 * 8 + j] = f2bf(W0[(k + j) * 512 + n]);   // W0[k][n], k<64
  }
  if (ntg < 4) { // W0 bwd: N=64 -> ntg 0..3, kc 0..15
    int t0 = (ntg * 16 + kc) * 64 + lane;
    #pragma unroll
    for (int j = 0; j < 8; ++j)
      p0b[t0 * 8 + j] = f2bf(W0[n * 512 + (k + j)]);   // W0[n][k], n<64
  }
}

// 512-wide GEMM K-loop: A (32x512 bf16) from single LDS buf, B frag-packed
// from L2 (contiguous 1KB per wave per load).
#define GEMM512(BP)                                                             \
  {                                                                             \
    _Pragma("unroll") for (int mt = 0; mt < 2; ++mt)                            \
      _Pragma("unroll") for (int nt = 0; nt < 8; ++nt)                          \
        acc[mt][nt] = (f32x4){0.f, 0.f, 0.f, 0.f};                              \
    const u16* bpw = (BP) + (wave << 16) + lane * 8;                            \
    _Pragma("unroll 2")                                                         \
    for (int kc = 0; kc < 16; ++kc) {                                           \
      s16x8 a0 = *(const s16x8*)(buf + ln * AST + kc * 32 + q * 8);             \
      s16x8 a1 = *(const s16x8*)(buf + (16 + ln) * AST + kc * 32 + q * 8);      \
      _Pragma("unroll")                                                         \
      for (int nt = 0; nt < 8; ++nt) {                                          \
        s16x8 b = *(const s16x8*)(bpw + ((nt * 16 + kc) << 9));                 \
        acc[0][nt] = MFMA_BF16(a0, b, acc[0][nt]);                              \
        acc[1][nt] = MFMA_BF16(a1, b, acc[1][nt]);                              \
      }                                                                         \
    }                                                                           \
  }

// block=256, 4 waves; single 33KB activation buffer -> 37.9KB LDS -> 4 blk/CU.
// __launch_bounds__(256,4): pin VGPR<=128 so occupancy stays 16 waves/CU.
__global__ __launch_bounds__(256, 4) void hnn_fused(
    const float* __restrict__ x,
    const float* __restrict__ bias0,
    const float* __restrict__ bias1,
    const float* __restrict__ bias2,
    const float* __restrict__ W3,
    const u16* __restrict__ ws,
    float* __restrict__ out)
{
  const u16* p0f = ws;
  const u16* p0b = p0f + D_IN * H_DIM;
  const u16* p1f = p0b + D_IN * H_DIM;
  const u16* p1b = p1f + H_DIM * H_DIM;
  const u16* p2f = p1b + H_DIM * H_DIM;
  const u16* p2b = p2f + H_DIM * H_DIM;

  __shared__ __align__(16) u16 xs[M_TILE * XST];    // 4.5 KB
  __shared__ __align__(16) u16 buf[M_TILE * AST];   // 32.5 KB

  const int tid  = threadIdx.x;
  const int wave = tid >> 6;
  const int lane = tid & 63;
  const int ln   = lane & 15;
  const int q    = lane >> 4;
  const int nwb  = wave * 128;
  const int row0 = blockIdx.x * M_TILE;

  // ---- stage x tile: 32x64 fp32 -> bf16 LDS ----
  {
    int e = tid * 8;
    int r = e >> 6, c = e & 63;
    const float4* src = (const float4*)(x + (size_t)(row0 + r) * D_IN + c);
    float4 f0 = src[0];
    float4 f1 = src[1];
    u16* dst = xs + r * XST + c;
    dst[0] = f2bf(f0.x); dst[1] = f2bf(f0.y); dst[2] = f2bf(f0.z); dst[3] = f2bf(f0.w);
    dst[4] = f2bf(f1.x); dst[5] = f2bf(f1.y); dst[6] = f2bf(f1.z); dst[7] = f2bf(f1.w);
  }
  __syncthreads();

  f32x4 acc[2][8];
  unsigned h0p[2][8][2];   // h0 bf16x2-packed, C-layout (for tanh' in bwd)
  unsigned h1p[2][8][2];
  float bias[8];

  // ================ GEMM0: z0 = x @ W0  (K=64, reads xs) ================
  #pragma unroll
  for (int nt = 0; nt < 8; ++nt) bias[nt] = bias0[nwb + nt * 16 + ln];
  #pragma unroll
  for (int mt = 0; mt < 2; ++mt)
    #pragma unroll
    for (int nt = 0; nt < 8; ++nt) acc[mt][nt] = (f32x4){0.f, 0.f, 0.f, 0.f};
  {
    const u16* bpw0 = p0f + (wave << 13) + lane * 8;
    #pragma unroll
    for (int kc = 0; kc < 2; ++kc) {
      s16x8 a0 = *(const s16x8*)(xs + ln * XST + kc * 32 + q * 8);
      s16x8 a1 = *(const s16x8*)(xs + (16 + ln) * XST + kc * 32 + q * 8);
      #pragma unroll
      for (int nt = 0; nt < 8; ++nt) {
        s16x8 b = *(const s16x8*)(bpw0 + ((nt * 2 + kc) << 9));
        acc[0][nt] = MFMA_BF16(a0, b, acc[0][nt]);
        acc[1][nt] = MFMA_BF16(a1, b, acc[1][nt]);
      }
    }
  }
  // epilogue: h0 = tanh(z0+b0) -> regs + buf (buf not yet read by anyone)
  #pragma unroll
  for (int mt = 0; mt < 2; ++mt)
    #pragma unroll
    for (int nt = 0; nt < 8; ++nt) {
      int col = nwb + nt * 16 + ln;
      u16 u[4];
      #pragma unroll
      for (int r = 0; r < 4; ++r) {
        float th = fast_tanh(acc[mt][nt][r] + bias[nt]);
        u[r] = f2bf(th);
        buf[(mt * 16 + q * 4 + r) * AST + col] = u[r];
      }
      h0p[mt][nt][0] = (unsigned)u[0] | ((unsigned)u[1] << 16);
      h0p[mt][nt][1] = (unsigned)u[2] | ((unsigned)u[3] << 16);
    }
  __syncthreads();

  // ================ GEMM1: z1 = h0 @ W1 ================
  #pragma unroll
  for (int nt = 0; nt < 8; ++nt) bias[nt] = bias1[nwb + nt * 16 + ln];
  GEMM512(p1f);
  __syncthreads();   // all waves done reading h0 before overwrite
  #pragma unroll
  for (int mt = 0; mt < 2; ++mt)
    #pragma unroll
    for (int nt = 0; nt < 8; ++nt) {
      int col = nwb + nt * 16 + ln;
      u16 u[4];
      #pragma unroll
      for (int r = 0; r < 4; ++r) {
        float th = fast_tanh(acc[mt][nt][r] + bias[nt]);
        u[r] = f2bf(th);
        buf[(mt * 16 + q * 4 + r) * AST + col] = u[r];
      }
      h1p[mt][nt][0] = (unsigned)u[0] | ((unsigned)u[1] << 16);
      h1p[mt][nt][1] = (unsigned)u[2] | ((unsigned)u[3] << 16);
    }
  __syncthreads();

  // ================ GEMM2: z2 = h1 @ W2 ; gz2 = W3*(1-h2^2) ================
  #pragma unroll
  for (int nt = 0; nt < 8; ++nt) bias[nt] = bias2[nwb + nt * 16 + ln];
  float w3v[8];
  #pragma unroll
  for (int nt = 0; nt < 8; ++nt) w3v[nt] = W3[nwb + nt * 16 + ln];
  GEMM512(p2f);
  __syncthreads();
  #pragma unroll
  for (int mt = 0; mt < 2; ++mt)
    #pragma unroll
    for (int nt = 0; nt < 8; ++nt) {
      int col = nwb + nt * 16 + ln;
      #pragma unroll
      for (int r = 0; r < 4; ++r) {
        float th = fast_tanh(acc[mt][nt][r] + bias[nt]);
        float gz = w3v[nt] * (1.0f - th * th);
        buf[(mt * 16 + q * 4 + r) * AST + col] = f2bf(gz);
      }
    }
  __syncthreads();

  // ================ GEMM3: g1 = gz2 @ W2^T ; gz1 = g1*(1-h1^2) ================
  GEMM512(p2b);
  __syncthreads();
  #pragma unroll
  for (int mt = 0; mt < 2; ++mt)
    #pragma unroll
    for (int nt = 0; nt < 8; ++nt) {
      int col = nwb + nt * 16 + ln;
      unsigned pa = h1p[mt][nt][0], pb = h1p[mt][nt][1];
      float hh[4] = { bfb2f(pa & 0xffffu), bfb2f(pa >> 16),
                      bfb2f(pb & 0xffffu), bfb2f(pb >> 16) };
      #pragma unroll
      for (int r = 0; r < 4; ++r) {
        float gz = acc[mt][nt][r] * (1.0f - hh[r] * hh[r]);
        buf[(mt * 16 + q * 4 + r) * AST + col] = f2bf(gz);
      }
    }
  __syncthreads();

  // ================ GEMM4: g0 = gz1 @ W1^T ; gz0 = g0*(1-h0^2) ================
  GEMM512(p1b);
  __syncthreads();
  #pragma unroll
  for (int mt = 0; mt < 2; ++mt)
    #pragma unroll
    for (int nt = 0; nt < 8; ++nt) {
      int col = nwb + nt * 16 + ln;
      unsigned pa = h0p[mt][nt][0], pb = h0p[mt][nt][1];
      float hh[4] = { bfb2f(pa & 0xffffu), bfb2f(pa >> 16),
                      bfb2f(pb & 0xffffu), bfb2f(pb >> 16) };
      #pragma unroll
      for (int r = 0; r < 4; ++r) {
        float gz = acc[mt][nt][r] * (1.0f - hh[r] * hh[r]);
        buf[(mt * 16 + q * 4 + r) * AST + col] = f2bf(gz);
      }
    }
  __syncthreads();

  // ================ GEMM5: gradH = gz0 @ W0^T (32x64), symplectic store ======
  {
    f32x4 acc5[2];
    acc5[0] = (f32x4){0.f, 0.f, 0.f, 0.f};
    acc5[1] = (f32x4){0.f, 0.f, 0.f, 0.f};
    const int mt5 = wave & 1;            // row half
    const int nb5 = (wave >> 1) * 32;    // gradH column base (0 or 32)
    const u16* bp5 = p0b + ((wave >> 1) << 14) + lane * 8;
    #pragma unroll 2
    for (int kc = 0; kc < 16; ++kc) {
      s16x8 a = *(const s16x8*)(buf + (mt5 * 16 + ln) * AST + kc * 32 + q * 8);
      #pragma unroll
      for (int nt = 0; nt < 2; ++nt) {
        s16x8 b = *(const s16x8*)(bp5 + ((nt * 16 + kc) << 9));
        acc5[nt] = MFMA_BF16(a, b, acc5[nt]);
      }
    }
    #pragma unroll
    for (int nt = 0; nt < 2; ++nt) {
      int g = nb5 + nt * 16 + ln;                 // gradH column
      int c = (g < 32) ? g + 32 : g - 32;         // out = concat(gradH[:,32:], -gradH[:,:32])
      float s = (g < 32) ? -1.0f : 1.0f;
      #pragma unroll
      for (int r = 0; r < 4; ++r) {
        int grow = row0 + mt5 * 16 + q * 4 + r;
        out[(size_t)grow * 64 + c] = s * acc5[nt][r];
      }
    }
  }
}

extern "C" void kernel_launch(void* const* d_in, const int* in_sizes, int n_in,
                              void* d_out, int out_size, void* d_ws, size_t ws_size,
                              hipStream_t stream) {
  // setup_inputs order: t, x, W0, b0, W1, b1, W2, b2, W3, b3
  const float* x  = (const float*)d_in[1];
  const float* W0 = (const float*)d_in[2];
  const float* b0 = (const float*)d_in[3];
  const float* W1 = (const float*)d_in[4];
  const float* b1 = (const float*)d_in[5];
  const float* W2 = (const float*)d_in[6];
  const float* b2 = (const float*)d_in[7];
  const float* W3 = (const float*)d_in[8];
  u16* ws = (u16*)d_ws;
  float* out = (float*)d_out;

  prep_weights<<<128, 256, 0, stream>>>(W0, W1, W2, ws);
  hnn_fused<<<65536 / M_TILE, 256, 0, stream>>>(x, b0, b1, b2, W3, ws, out);
}

// Round 4
// 374.777 us; speedup vs baseline: 1.1062x; 1.1062x over previous
//
#include <hip/hip_runtime.h>
#include <hip/hip_bf16.h>

typedef unsigned short u16;
typedef short s16x8 __attribute__((ext_vector_type(8)));
typedef float f32x4 __attribute__((ext_vector_type(4)));

#define MFMA_BF16(a, b, c) __builtin_amdgcn_mfma_f32_16x16x32_bf16((a), (b), (c), 0, 0, 0)

static constexpr int D_IN   = 64;
static constexpr int H_DIM  = 512;
static constexpr int M_TILE = 32;
static constexpr int AST    = 520;  // LDS row stride (bf16)
static constexpr int XST    = 72;   // LDS row stride for x tile

__device__ __forceinline__ u16 f2bf(float f) {
  unsigned u = __builtin_bit_cast(unsigned, f);
  u += 0x7fffu + ((u >> 16) & 1u);   // RNE
  return (u16)(u >> 16);
}
__device__ __forceinline__ float bfb2f(unsigned bits16) {
  return __builtin_bit_cast(float, bits16 << 16);
}
__device__ __forceinline__ float fast_tanh(float x) {
  float e = __expf(2.0f * x);
  return 1.0f - 2.0f * __builtin_amdgcn_rcpf(e + 1.0f);
}

// ---- prep: fp32 weights -> bf16, packed in MFMA-B-fragment order ----
// For each (ntg = 16-col tile, kc = 32-wide K chunk): 512 elems stored as
// lane*8 contiguous, lane=(q*16+ln), elem j -> B[k=kc*32+q*8+j][n=ntg*16+ln].
// ws layout (bf16): p0f[64x512] p0b[512x64] p1f p1b p2f p2b  (~2.2MB)
__global__ void prep_weights(const float* __restrict__ W0,
                             const float* __restrict__ W1,
                             const float* __restrict__ W2,
                             u16* __restrict__ ws) {
  u16* p0f = ws;                       // fwd W0: K=64,  N=512
  u16* p0b = p0f + D_IN * H_DIM;       // bwd W0^T: K=512, N=64
  u16* p1f = p0b + D_IN * H_DIM;
  u16* p1b = p1f + H_DIM * H_DIM;
  u16* p2f = p1b + H_DIM * H_DIM;
  u16* p2b = p2f + H_DIM * H_DIM;

  int t = blockIdx.x * 256 + threadIdx.x;   // 32768 threads total
  int lane = t & 63;
  int kc   = (t >> 6) & 15;
  int ntg  = t >> 10;                       // 0..31
  int ln = lane & 15, q = lane >> 4;
  int n = ntg * 16 + ln;
  int k = kc * 32 + q * 8;

  #pragma unroll
  for (int j = 0; j < 8; ++j) {
    p1f[t * 8 + j] = f2bf(W1[(k + j) * 512 + n]);
    p2f[t * 8 + j] = f2bf(W2[(k + j) * 512 + n]);
    p1b[t * 8 + j] = f2bf(W1[n * 512 + (k + j)]);
    p2b[t * 8 + j] = f2bf(W2[n * 512 + (k + j)]);
  }
  if (kc < 2) {  // W0 fwd: K=64 -> kc in {0,1}, ntg 0..31
    int t0 = (ntg * 2 + kc) * 64 + lane;
    #pragma unroll
    for (int j = 0; j < 8; ++j)
      p0f[t0 * 8 + j] = f2bf(W0[(k + j) * 512 + n]);   // W0[k][n], k<64
  }
  if (ntg < 4) { // W0 bwd: N=64 -> ntg 0..3, kc 0..15
    int t0 = (ntg * 16 + kc) * 64 + lane;
    #pragma unroll
    for (int j = 0; j < 8; ++j)
      p0b[t0 * 8 + j] = f2bf(W0[n * 512 + (k + j)]);   // W0[n][k], n<64
  }
}

// 512-wide GEMM K-loop: A (32x512 bf16) from single LDS buf, B frag-packed
// from L2 (contiguous 1KB per wave per load).
#define GEMM512(BP)                                                             \
  {                                                                             \
    _Pragma("unroll") for (int mt = 0; mt < 2; ++mt)                            \
      _Pragma("unroll") for (int nt = 0; nt < 8; ++nt)                          \
        acc[mt][nt] = (f32x4){0.f, 0.f, 0.f, 0.f};                              \
    const u16* bpw = (BP) + (wave << 16) + lane * 8;                            \
    _Pragma("unroll 2")                                                         \
    for (int kc = 0; kc < 16; ++kc) {                                           \
      s16x8 a0 = *(const s16x8*)(buf + ln * AST + kc * 32 + q * 8);             \
      s16x8 a1 = *(const s16x8*)(buf + (16 + ln) * AST + kc * 32 + q * 8);      \
      _Pragma("unroll")                                                         \
      for (int nt = 0; nt < 8; ++nt) {                                          \
        s16x8 b = *(const s16x8*)(bpw + ((nt * 16 + kc) << 9));                 \
        acc[0][nt] = MFMA_BF16(a0, b, acc[0][nt]);                              \
        acc[1][nt] = MFMA_BF16(a1, b, acc[1][nt]);                              \
      }                                                                         \
    }                                                                           \
  }

// Single 33KB activation buffer -> 37.9KB LDS -> LDS allows 4 blk/CU.
// __launch_bounds__(256,2): round-2 evidence this yields exactly 128 VGPR,
// no spills; 128 VGPR -> 4 waves/SIMD -> 4 blocks/CU resident.
// (256,4) clamped to 64 VGPR and spilled accumulators: FETCH 17->147MB. Never again.
__global__ __launch_bounds__(256, 2) void hnn_fused(
    const float* __restrict__ x,
    const float* __restrict__ bias0,
    const float* __restrict__ bias1,
    const float* __restrict__ bias2,
    const float* __restrict__ W3,
    const u16* __restrict__ ws,
    float* __restrict__ out)
{
  const u16* p0f = ws;
  const u16* p0b = p0f + D_IN * H_DIM;
  const u16* p1f = p0b + D_IN * H_DIM;
  const u16* p1b = p1f + H_DIM * H_DIM;
  const u16* p2f = p1b + H_DIM * H_DIM;
  const u16* p2b = p2f + H_DIM * H_DIM;

  __shared__ __align__(16) u16 xs[M_TILE * XST];    // 4.5 KB
  __shared__ __align__(16) u16 buf[M_TILE * AST];   // 32.5 KB

  const int tid  = threadIdx.x;
  const int wave = tid >> 6;
  const int lane = tid & 63;
  const int ln   = lane & 15;
  const int q    = lane >> 4;
  const int nwb  = wave * 128;
  const int row0 = blockIdx.x * M_TILE;

  // ---- stage x tile: 32x64 fp32 -> bf16 LDS ----
  {
    int e = tid * 8;
    int r = e >> 6, c = e & 63;
    const float4* src = (const float4*)(x + (size_t)(row0 + r) * D_IN + c);
    float4 f0 = src[0];
    float4 f1 = src[1];
    u16* dst = xs + r * XST + c;
    dst[0] = f2bf(f0.x); dst[1] = f2bf(f0.y); dst[2] = f2bf(f0.z); dst[3] = f2bf(f0.w);
    dst[4] = f2bf(f1.x); dst[5] = f2bf(f1.y); dst[6] = f2bf(f1.z); dst[7] = f2bf(f1.w);
  }
  __syncthreads();

  f32x4 acc[2][8];
  unsigned h0p[2][8][2];   // h0 bf16x2-packed, C-layout (for tanh' in bwd)
  unsigned h1p[2][8][2];
  float bias[8];

  // ================ GEMM0: z0 = x @ W0  (K=64, reads xs) ================
  #pragma unroll
  for (int nt = 0; nt < 8; ++nt) bias[nt] = bias0[nwb + nt * 16 + ln];
  #pragma unroll
  for (int mt = 0; mt < 2; ++mt)
    #pragma unroll
    for (int nt = 0; nt < 8; ++nt) acc[mt][nt] = (f32x4){0.f, 0.f, 0.f, 0.f};
  {
    const u16* bpw0 = p0f + (wave << 13) + lane * 8;
    #pragma unroll
    for (int kc = 0; kc < 2; ++kc) {
      s16x8 a0 = *(const s16x8*)(xs + ln * XST + kc * 32 + q * 8);
      s16x8 a1 = *(const s16x8*)(xs + (16 + ln) * XST + kc * 32 + q * 8);
      #pragma unroll
      for (int nt = 0; nt < 8; ++nt) {
        s16x8 b = *(const s16x8*)(bpw0 + ((nt * 2 + kc) << 9));
        acc[0][nt] = MFMA_BF16(a0, b, acc[0][nt]);
        acc[1][nt] = MFMA_BF16(a1, b, acc[1][nt]);
      }
    }
  }
  // epilogue: h0 = tanh(z0+b0) -> regs + buf (buf not yet read by anyone)
  #pragma unroll
  for (int mt = 0; mt < 2; ++mt)
    #pragma unroll
    for (int nt = 0; nt < 8; ++nt) {
      int col = nwb + nt * 16 + ln;
      u16 u[4];
      #pragma unroll
      for (int r = 0; r < 4; ++r) {
        float th = fast_tanh(acc[mt][nt][r] + bias[nt]);
        u[r] = f2bf(th);
        buf[(mt * 16 + q * 4 + r) * AST + col] = u[r];
      }
      h0p[mt][nt][0] = (unsigned)u[0] | ((unsigned)u[1] << 16);
      h0p[mt][nt][1] = (unsigned)u[2] | ((unsigned)u[3] << 16);
    }
  __syncthreads();

  // ================ GEMM1: z1 = h0 @ W1 ================
  #pragma unroll
  for (int nt = 0; nt < 8; ++nt) bias[nt] = bias1[nwb + nt * 16 + ln];
  GEMM512(p1f);
  __syncthreads();   // all waves done reading h0 before overwrite
  #pragma unroll
  for (int mt = 0; mt < 2; ++mt)
    #pragma unroll
    for (int nt = 0; nt < 8; ++nt) {
      int col = nwb + nt * 16 + ln;
      u16 u[4];
      #pragma unroll
      for (int r = 0; r < 4; ++r) {
        float th = fast_tanh(acc[mt][nt][r] + bias[nt]);
        u[r] = f2bf(th);
        buf[(mt * 16 + q * 4 + r) * AST + col] = u[r];
      }
      h1p[mt][nt][0] = (unsigned)u[0] | ((unsigned)u[1] << 16);
      h1p[mt][nt][1] = (unsigned)u[2] | ((unsigned)u[3] << 16);
    }
  __syncthreads();

  // ================ GEMM2: z2 = h1 @ W2 ; gz2 = W3*(1-h2^2) ================
  #pragma unroll
  for (int nt = 0; nt < 8; ++nt) bias[nt] = bias2[nwb + nt * 16 + ln];
  float w3v[8];
  #pragma unroll
  for (int nt = 0; nt < 8; ++nt) w3v[nt] = W3[nwb + nt * 16 + ln];
  GEMM512(p2f);
  __syncthreads();
  #pragma unroll
  for (int mt = 0; mt < 2; ++mt)
    #pragma unroll
    for (int nt = 0; nt < 8; ++nt) {
      int col = nwb + nt * 16 + ln;
      #pragma unroll
      for (int r = 0; r < 4; ++r) {
        float th = fast_tanh(acc[mt][nt][r] + bias[nt]);
        float gz = w3v[nt] * (1.0f - th * th);
        buf[(mt * 16 + q * 4 + r) * AST + col] = f2bf(gz);
      }
    }
  __syncthreads();

  // ================ GEMM3: g1 = gz2 @ W2^T ; gz1 = g1*(1-h1^2) ================
  GEMM512(p2b);
  __syncthreads();
  #pragma unroll
  for (int mt = 0; mt < 2; ++mt)
    #pragma unroll
    for (int nt = 0; nt < 8; ++nt) {
      int col = nwb + nt * 16 + ln;
      unsigned pa = h1p[mt][nt][0], pb = h1p[mt][nt][1];
      float hh[4] = { bfb2f(pa & 0xffffu), bfb2f(pa >> 16),
                      bfb2f(pb & 0xffffu), bfb2f(pb >> 16) };
      #pragma unroll
      for (int r = 0; r < 4; ++r) {
        float gz = acc[mt][nt][r] * (1.0f - hh[r] * hh[r]);
        buf[(mt * 16 + q * 4 + r) * AST + col] = f2bf(gz);
      }
    }
  __syncthreads();

  // ================ GEMM4: g0 = gz1 @ W1^T ; gz0 = g0*(1-h0^2) ================
  GEMM512(p1b);
  __syncthreads();
  #pragma unroll
  for (int mt = 0; mt < 2; ++mt)
    #pragma unroll
    for (int nt = 0; nt < 8; ++nt) {
      int col = nwb + nt * 16 + ln;
      unsigned pa = h0p[mt][nt][0], pb = h0p[mt][nt][1];
      float hh[4] = { bfb2f(pa & 0xffffu), bfb2f(pa >> 16),
                      bfb2f(pb & 0xffffu), bfb2f(pb >> 16) };
      #pragma unroll
      for (int r = 0; r < 4; ++r) {
        float gz = acc[mt][nt][r] * (1.0f - hh[r] * hh[r]);
        buf[(mt * 16 + q * 4 + r) * AST + col] = f2bf(gz);
      }
    }
  __syncthreads();

  // ================ GEMM5: gradH = gz0 @ W0^T (32x64), symplectic store ======
  {
    f32x4 acc5[2];
    acc5[0] = (f32x4){0.f, 0.f, 0.f, 0.f};
    acc5[1] = (f32x4){0.f, 0.f, 0.f, 0.f};
    const int mt5 = wave & 1;            // row half
    const int nb5 = (wave >> 1) * 32;    // gradH column base (0 or 32)
    const u16* bp5 = p0b + ((wave >> 1) << 14) + lane * 8;
    #pragma unroll 2
    for (int kc = 0; kc < 16; ++kc) {
      s16x8 a = *(const s16x8*)(buf + (mt5 * 16 + ln) * AST + kc * 32 + q * 8);
      #pragma unroll
      for (int nt = 0; nt < 2; ++nt) {
        s16x8 b = *(const s16x8*)(bp5 + ((nt * 16 + kc) << 9));
        acc5[nt] = MFMA_BF16(a, b, acc5[nt]);
      }
    }
    #pragma unroll
    for (int nt = 0; nt < 2; ++nt) {
      int g = nb5 + nt * 16 + ln;                 // gradH column
      int c = (g < 32) ? g + 32 : g - 32;         // out = concat(gradH[:,32:], -gradH[:,:32])
      float s = (g < 32) ? -1.0f : 1.0f;
      #pragma unroll
      for (int r = 0; r < 4; ++r) {
        int grow = row0 + mt5 * 16 + q * 4 + r;
        out[(size_t)grow * 64 + c] = s * acc5[nt][r];
      }
    }
  }
}

extern "C" void kernel_launch(void* const* d_in, const int* in_sizes, int n_in,
                              void* d_out, int out_size, void* d_ws, size_t ws_size,
                              hipStream_t stream) {
  // setup_inputs order: t, x, W0, b0, W1, b1, W2, b2, W3, b3
  const float* x  = (const float*)d_in[1];
  const float* W0 = (const float*)d_in[2];
  const float* b0 = (const float*)d_in[3];
  const float* W1 = (const float*)d_in[4];
  const float* b1 = (const float*)d_in[5];
  const float* W2 = (const float*)d_in[6];
  const float* b2 = (const float*)d_in[7];
  const float* W3 = (const float*)d_in[8];
  u16* ws = (u16*)d_ws;
  float* out = (float*)d_out;

  prep_weights<<<128, 256, 0, stream>>>(W0, W1, W2, ws);
  hnn_fused<<<65536 / M_TILE, 256, 0, stream>>>(x, b0, b1, b2, W3, ws, out);
}

// Round 5
// 349.106 us; speedup vs baseline: 1.1875x; 1.0735x over previous
//
#include <hip/hip_runtime.h>
#include <hip/hip_bf16.h>

typedef unsigned short u16;
typedef short s16x8 __attribute__((ext_vector_type(8)));
typedef float f32x4 __attribute__((ext_vector_type(4)));

#define MFMA_BF16(a, b, c) __builtin_amdgcn_mfma_f32_16x16x32_bf16((a), (b), (c), 0, 0, 0)

static constexpr int D_IN   = 64;
static constexpr int H_DIM  = 512;
static constexpr int M_TILE = 32;
static constexpr int AST    = 520;  // LDS row stride (bf16)
static constexpr int XST    = 72;   // LDS row stride for x tile

__device__ __forceinline__ u16 f2bf(float f) {
  unsigned u = __builtin_bit_cast(unsigned, f);
  u += 0x7fffu + ((u >> 16) & 1u);   // RNE
  return (u16)(u >> 16);
}
__device__ __forceinline__ float bfb2f(unsigned bits16) {
  return __builtin_bit_cast(float, bits16 << 16);
}
__device__ __forceinline__ float fast_tanh(float x) {
  float e = __expf(2.0f * x);
  return 1.0f - 2.0f * __builtin_amdgcn_rcpf(e + 1.0f);
}

// ---- prep: fp32 weights -> bf16, packed in MFMA-B-fragment order ----
// For each (ntg = 16-col tile, kc = 32-wide K chunk): 512 elems stored as
// lane*8 contiguous, lane=(q*16+ln), elem j -> B[k=kc*32+q*8+j][n=ntg*16+ln].
// ws layout (bf16): p0f[64x512] p0b[512x64] p1f p1b p2f p2b  (~2.2MB)
__global__ void prep_weights(const float* __restrict__ W0,
                             const float* __restrict__ W1,
                             const float* __restrict__ W2,
                             u16* __restrict__ ws) {
  u16* p0f = ws;                       // fwd W0: K=64,  N=512
  u16* p0b = p0f + D_IN * H_DIM;       // bwd W0^T: K=512, N=64
  u16* p1f = p0b + D_IN * H_DIM;
  u16* p1b = p1f + H_DIM * H_DIM;
  u16* p2f = p1b + H_DIM * H_DIM;
  u16* p2b = p2f + H_DIM * H_DIM;

  int t = blockIdx.x * 256 + threadIdx.x;   // 32768 threads total
  int lane = t & 63;
  int kc   = (t >> 6) & 15;
  int ntg  = t >> 10;                       // 0..31
  int ln = lane & 15, q = lane >> 4;
  int n = ntg * 16 + ln;
  int k = kc * 32 + q * 8;

  #pragma unroll
  for (int j = 0; j < 8; ++j) {
    p1f[t * 8 + j] = f2bf(W1[(k + j) * 512 + n]);
    p2f[t * 8 + j] = f2bf(W2[(k + j) * 512 + n]);
    p1b[t * 8 + j] = f2bf(W1[n * 512 + (k + j)]);
    p2b[t * 8 + j] = f2bf(W2[n * 512 + (k + j)]);
  }
  if (kc < 2) {  // W0 fwd: K=64 -> kc in {0,1}, ntg 0..31
    int t0 = (ntg * 2 + kc) * 64 + lane;
    #pragma unroll
    for (int j = 0; j < 8; ++j)
      p0f[t0 * 8 + j] = f2bf(W0[(k + j) * 512 + n]);   // W0[k][n], k<64
  }
  if (ntg < 4) { // W0 bwd: N=64 -> ntg 0..3, kc 0..15
    int t0 = (ntg * 16 + kc) * 64 + lane;
    #pragma unroll
    for (int j = 0; j < 8; ++j)
      p0b[t0 * 8 + j] = f2bf(W0[n * 512 + (k + j)]);   // W0[n][k], n<64
  }
}

// 512-wide GEMM K-loop, 8-wave block: each wave owns 32x64 output (4 n-tiles).
// A (32x512 bf16) from single LDS buf, B frag-packed from L2 (contiguous 1KB
// per wave per load).
#define GEMM512(BP)                                                             \
  {                                                                             \
    _Pragma("unroll") for (int mt = 0; mt < 2; ++mt)                            \
      _Pragma("unroll") for (int nt = 0; nt < 4; ++nt)                          \
        acc[mt][nt] = (f32x4){0.f, 0.f, 0.f, 0.f};                              \
    const u16* bpw = (BP) + (wave << 15) + lane * 8;                            \
    _Pragma("unroll 2")                                                         \
    for (int kc = 0; kc < 16; ++kc) {                                           \
      s16x8 a0 = *(const s16x8*)(buf + ln * AST + kc * 32 + q * 8);             \
      s16x8 a1 = *(const s16x8*)(buf + (16 + ln) * AST + kc * 32 + q * 8);      \
      _Pragma("unroll")                                                         \
      for (int nt = 0; nt < 4; ++nt) {                                          \
        s16x8 b = *(const s16x8*)(bpw + ((nt * 16 + kc) << 9));                 \
        acc[0][nt] = MFMA_BF16(a0, b, acc[0][nt]);                              \
        acc[1][nt] = MFMA_BF16(a1, b, acc[1][nt]);                              \
      }                                                                         \
    }                                                                           \
  }

// block=512 (8 waves), each wave 32x64 slice -> acc[2][4]=32 regs, total
// footprint ~110 regs: genuinely fits the 128-reg budget that
// __launch_bounds__(512,4) demands -> 4 waves/SIMD, 2 blocks/CU, LDS 75.8KB.
// (round-3 lesson: only demand occupancy the footprint actually fits.)
__global__ __launch_bounds__(512, 4) void hnn_fused(
    const float* __restrict__ x,
    const float* __restrict__ bias0,
    const float* __restrict__ bias1,
    const float* __restrict__ bias2,
    const float* __restrict__ W3,
    const u16* __restrict__ ws,
    float* __restrict__ out)
{
  const u16* p0f = ws;
  const u16* p0b = p0f + D_IN * H_DIM;
  const u16* p1f = p0b + D_IN * H_DIM;
  const u16* p1b = p1f + H_DIM * H_DIM;
  const u16* p2f = p1b + H_DIM * H_DIM;
  const u16* p2b = p2f + H_DIM * H_DIM;

  __shared__ __align__(16) u16 xs[M_TILE * XST];    // 4.5 KB
  __shared__ __align__(16) u16 buf[M_TILE * AST];   // 32.5 KB

  const int tid  = threadIdx.x;
  const int wave = tid >> 6;      // 0..7
  const int lane = tid & 63;
  const int ln   = lane & 15;
  const int q    = lane >> 4;
  const int nwb  = wave * 64;     // wave's 64-col slice
  const int row0 = blockIdx.x * M_TILE;

  // ---- stage x tile: 32x64 fp32 -> bf16 LDS (512 thr x 4 elems) ----
  {
    int e = tid * 4;
    int r = e >> 6, c = e & 63;
    float4 f0 = *(const float4*)(x + (size_t)(row0 + r) * D_IN + c);
    u16* dst = xs + r * XST + c;
    dst[0] = f2bf(f0.x); dst[1] = f2bf(f0.y); dst[2] = f2bf(f0.z); dst[3] = f2bf(f0.w);
  }
  __syncthreads();

  f32x4 acc[2][4];
  unsigned h0p[2][4][2];   // h0 bf16x2-packed, C-layout (for tanh' in bwd)
  unsigned h1p[2][4][2];
  float bias[4];

  // ================ GEMM0: z0 = x @ W0  (K=64, reads xs) ================
  #pragma unroll
  for (int nt = 0; nt < 4; ++nt) bias[nt] = bias0[nwb + nt * 16 + ln];
  #pragma unroll
  for (int mt = 0; mt < 2; ++mt)
    #pragma unroll
    for (int nt = 0; nt < 4; ++nt) acc[mt][nt] = (f32x4){0.f, 0.f, 0.f, 0.f};
  {
    const u16* bpw0 = p0f + (wave << 12) + lane * 8;  // wave*4 ntg * 2 kc * 512
    #pragma unroll
    for (int kc = 0; kc < 2; ++kc) {
      s16x8 a0 = *(const s16x8*)(xs + ln * XST + kc * 32 + q * 8);
      s16x8 a1 = *(const s16x8*)(xs + (16 + ln) * XST + kc * 32 + q * 8);
      #pragma unroll
      for (int nt = 0; nt < 4; ++nt) {
        s16x8 b = *(const s16x8*)(bpw0 + ((nt * 2 + kc) << 9));
        acc[0][nt] = MFMA_BF16(a0, b, acc[0][nt]);
        acc[1][nt] = MFMA_BF16(a1, b, acc[1][nt]);
      }
    }
  }
  // epilogue: h0 = tanh(z0+b0) -> regs + buf (buf not yet read by anyone)
  #pragma unroll
  for (int mt = 0; mt < 2; ++mt)
    #pragma unroll
    for (int nt = 0; nt < 4; ++nt) {
      int col = nwb + nt * 16 + ln;
      u16 u[4];
      #pragma unroll
      for (int r = 0; r < 4; ++r) {
        float th = fast_tanh(acc[mt][nt][r] + bias[nt]);
        u[r] = f2bf(th);
        buf[(mt * 16 + q * 4 + r) * AST + col] = u[r];
      }
      h0p[mt][nt][0] = (unsigned)u[0] | ((unsigned)u[1] << 16);
      h0p[mt][nt][1] = (unsigned)u[2] | ((unsigned)u[3] << 16);
    }
  __syncthreads();

  // ================ GEMM1: z1 = h0 @ W1 ================
  #pragma unroll
  for (int nt = 0; nt < 4; ++nt) bias[nt] = bias1[nwb + nt * 16 + ln];
  GEMM512(p1f);
  __syncthreads();   // all waves done reading h0 before overwrite
  #pragma unroll
  for (int mt = 0; mt < 2; ++mt)
    #pragma unroll
    for (int nt = 0; nt < 4; ++nt) {
      int col = nwb + nt * 16 + ln;
      u16 u[4];
      #pragma unroll
      for (int r = 0; r < 4; ++r) {
        float th = fast_tanh(acc[mt][nt][r] + bias[nt]);
        u[r] = f2bf(th);
        buf[(mt * 16 + q * 4 + r) * AST + col] = u[r];
      }
      h1p[mt][nt][0] = (unsigned)u[0] | ((unsigned)u[1] << 16);
      h1p[mt][nt][1] = (unsigned)u[2] | ((unsigned)u[3] << 16);
    }
  __syncthreads();

  // ================ GEMM2: z2 = h1 @ W2 ; gz2 = W3*(1-h2^2) ================
  #pragma unroll
  for (int nt = 0; nt < 4; ++nt) bias[nt] = bias2[nwb + nt * 16 + ln];
  float w3v[4];
  #pragma unroll
  for (int nt = 0; nt < 4; ++nt) w3v[nt] = W3[nwb + nt * 16 + ln];
  GEMM512(p2f);
  __syncthreads();
  #pragma unroll
  for (int mt = 0; mt < 2; ++mt)
    #pragma unroll
    for (int nt = 0; nt < 4; ++nt) {
      int col = nwb + nt * 16 + ln;
      #pragma unroll
      for (int r = 0; r < 4; ++r) {
        float th = fast_tanh(acc[mt][nt][r] + bias[nt]);
        float gz = w3v[nt] * (1.0f - th * th);
        buf[(mt * 16 + q * 4 + r) * AST + col] = f2bf(gz);
      }
    }
  __syncthreads();

  // ================ GEMM3: g1 = gz2 @ W2^T ; gz1 = g1*(1-h1^2) ================
  GEMM512(p2b);
  __syncthreads();
  #pragma unroll
  for (int mt = 0; mt < 2; ++mt)
    #pragma unroll
    for (int nt = 0; nt < 4; ++nt) {
      int col = nwb + nt * 16 + ln;
      unsigned pa = h1p[mt][nt][0], pb = h1p[mt][nt][1];
      float hh[4] = { bfb2f(pa & 0xffffu), bfb2f(pa >> 16),
                      bfb2f(pb & 0xffffu), bfb2f(pb >> 16) };
      #pragma unroll
      for (int r = 0; r < 4; ++r) {
        float gz = acc[mt][nt][r] * (1.0f - hh[r] * hh[r]);
        buf[(mt * 16 + q * 4 + r) * AST + col] = f2bf(gz);
      }
    }
  __syncthreads();

  // ================ GEMM4: g0 = gz1 @ W1^T ; gz0 = g0*(1-h0^2) ================
  GEMM512(p1b);
  __syncthreads();
  #pragma unroll
  for (int mt = 0; mt < 2; ++mt)
    #pragma unroll
    for (int nt = 0; nt < 4; ++nt) {
      int col = nwb + nt * 16 + ln;
      unsigned pa = h0p[mt][nt][0], pb = h0p[mt][nt][1];
      float hh[4] = { bfb2f(pa & 0xffffu), bfb2f(pa >> 16),
                      bfb2f(pb & 0xffffu), bfb2f(pb >> 16) };
      #pragma unroll
      for (int r = 0; r < 4; ++r) {
        float gz = acc[mt][nt][r] * (1.0f - hh[r] * hh[r]);
        buf[(mt * 16 + q * 4 + r) * AST + col] = f2bf(gz);
      }
    }
  __syncthreads();

  // ================ GEMM5: gradH = gz0 @ W0^T (32x64), symplectic store ======
  // 8 waves x one 16x16 tile: row half = wave&1, col tile = wave>>2? no:
  // col tile ntg = wave>>1 (0..3), 16 cols each.
  {
    f32x4 acc5 = (f32x4){0.f, 0.f, 0.f, 0.f};
    const int mt5 = wave & 1;            // row half
    const int nb5 = (wave >> 1) * 16;    // gradH column tile base
    const u16* bp5 = p0b + ((wave >> 1) << 13) + lane * 8;  // ntg*16kc*512
    #pragma unroll 2
    for (int kc = 0; kc < 16; ++kc) {
      s16x8 a = *(const s16x8*)(buf + (mt5 * 16 + ln) * AST + kc * 32 + q * 8);
      s16x8 b = *(const s16x8*)(bp5 + (kc << 9));
      acc5 = MFMA_BF16(a, b, acc5);
    }
    int g = nb5 + ln;                           // gradH column
    int c = (g < 32) ? g + 32 : g - 32;         // out = concat(gradH[:,32:], -gradH[:,:32])
    float s = (g < 32) ? -1.0f : 1.0f;
    #pragma unroll
    for (int r = 0; r < 4; ++r) {
      int grow = row0 + mt5 * 16 + q * 4 + r;
      out[(size_t)grow * 64 + c] = s * acc5[r];
    }
  }
}

extern "C" void kernel_launch(void* const* d_in, const int* in_sizes, int n_in,
                              void* d_out, int out_size, void* d_ws, size_t ws_size,
                              hipStream_t stream) {
  // setup_inputs order: t, x, W0, b0, W1, b1, W2, b2, W3, b3
  const float* x  = (const float*)d_in[1];
  const float* W0 = (const float*)d_in[2];
  const float* b0 = (const float*)d_in[3];
  const float* W1 = (const float*)d_in[4];
  const float* b1 = (const float*)d_in[5];
  const float* W2 = (const float*)d_in[6];
  const float* b2 = (const float*)d_in[7];
  const float* W3 = (const float*)d_in[8];
  u16* ws = (u16*)d_ws;
  float* out = (float*)d_out;

  prep_weights<<<128, 256, 0, stream>>>(W0, W1, W2, ws);
  hnn_fused<<<65536 / M_TILE, 512, 0, stream>>>(x, b0, b1, b2, W3, ws, out);
}

// Round 7
// 301.677 us; speedup vs baseline: 1.3742x; 1.1572x over previous
//
#include <hip/hip_runtime.h>
#include <hip/hip_bf16.h>

typedef unsigned short u16;
typedef short s16x8 __attribute__((ext_vector_type(8)));
typedef float f32x4 __attribute__((ext_vector_type(4)));

#define MFMA_BF16(a, b, c) __builtin_amdgcn_mfma_f32_16x16x32_bf16((a), (b), (c), 0, 0, 0)

static constexpr int D_IN   = 64;
static constexpr int H_DIM  = 512;
static constexpr int M_TILE = 32;
static constexpr int AST    = 520;  // LDS row stride (bf16)
static constexpr int XST    = 72;   // LDS row stride for x tile

// s_waitcnt immediates (gfx9 encoding): vmcnt[3:0]|exp[6:4]|lgkm[11:8]|vmhi[15:14]
#define WAIT_VM0   0x0F70  // vmcnt(0), lgkm/exp unconstrained
#define WAIT_LGKM0 0xC07F  // lgkmcnt(0), vm/exp unconstrained

__device__ __forceinline__ u16 f2bf(float f) {
  unsigned u = __builtin_bit_cast(unsigned, f);
  u += 0x7fffu + ((u >> 16) & 1u);   // RNE
  return (u16)(u >> 16);
}
__device__ __forceinline__ float bfb2f(unsigned bits16) {
  return __builtin_bit_cast(float, bits16 << 16);
}
__device__ __forceinline__ float fast_tanh(float x) {
  float e = __expf(2.0f * x);
  return 1.0f - 2.0f * __builtin_amdgcn_rcpf(e + 1.0f);
}
// async global->LDS DMA, 16B/lane: lds dest = wave-uniform base + lane*16
__device__ __forceinline__ void dma16(const u16* g, u16* l) {
  __builtin_amdgcn_global_load_lds(
      (const __attribute__((address_space(1))) unsigned int*)g,
      (__attribute__((address_space(3))) unsigned int*)l, 16, 0, 0);
}

// ---- prep: fp32 weights -> bf16, packed in MFMA-B-fragment order ----
// For each (ntg = 16-col tile, kc = 32-wide K chunk): 512 elems stored as
// lane*8 contiguous, lane=(q*16+ln), elem j -> B[k=kc*32+q*8+j][n=ntg*16+ln].
// ws layout (bf16): p0f[64x512] p0b[512x64] p1f p1b p2f p2b  (~2.2MB)
__global__ void prep_weights(const float* __restrict__ W0,
                             const float* __restrict__ W1,
                             const float* __restrict__ W2,
                             u16* __restrict__ ws) {
  u16* p0f = ws;                       // fwd W0: K=64,  N=512
  u16* p0b = p0f + D_IN * H_DIM;       // bwd W0^T: K=512, N=64
  u16* p1f = p0b + D_IN * H_DIM;
  u16* p1b = p1f + H_DIM * H_DIM;
  u16* p2f = p1b + H_DIM * H_DIM;
  u16* p2b = p2f + H_DIM * H_DIM;

  int t = blockIdx.x * 256 + threadIdx.x;   // 32768 threads total
  int lane = t & 63;
  int kc   = (t >> 6) & 15;
  int ntg  = t >> 10;                       // 0..31
  int ln = lane & 15, q = lane >> 4;
  int n = ntg * 16 + ln;
  int k = kc * 32 + q * 8;

  #pragma unroll
  for (int j = 0; j < 8; ++j) {
    p1f[t * 8 + j] = f2bf(W1[(k + j) * 512 + n]);
    p2f[t * 8 + j] = f2bf(W2[(k + j) * 512 + n]);
    p1b[t * 8 + j] = f2bf(W1[n * 512 + (k + j)]);
    p2b[t * 8 + j] = f2bf(W2[n * 512 + (k + j)]);
  }
  if (kc < 2) {  // W0 fwd: K=64 -> kc in {0,1}, ntg 0..31
    int t0 = (ntg * 2 + kc) * 64 + lane;
    #pragma unroll
    for (int j = 0; j < 8; ++j)
      p0f[t0 * 8 + j] = f2bf(W0[(k + j) * 512 + n]);   // W0[k][n], k<64
  }
  if (ntg < 4) { // W0 bwd: N=64 -> ntg 0..3, kc 0..15
    int t0 = (ntg * 16 + kc) * 64 + lane;
    #pragma unroll
    for (int j = 0; j < 8; ++j)
      p0b[t0 * 8 + j] = f2bf(W0[n * 512 + (k + j)]);   // W0[n][k], n<64
  }
}

// stage chunk kc of a 512-wide B: wave stages its OWN 8 ntg-segments (1KB each)
// into its private bs region. src segment (ntg,kc) is contiguous 1KB.
#define ISSUE_CHUNK(BP, KC)                                                     \
  {                                                                             \
    const u16* _src = (BP) + ((size_t)(wave * 8) * 16 + (KC)) * 512 + lane * 8; \
    _Pragma("unroll")                                                           \
    for (int s = 0; s < 8; ++s)                                                 \
      dma16(_src + s * (16 * 512), &bs[(wave * 8 + s) * 512]);                  \
  }

// 512-wide GEMM K-loop, DMA-staged B. No barriers inside: each wave's bs slots
// are produced and consumed only by itself; waves de-phase across kc and fill
// each other's DMA-latency stalls (m114 overlap). Chunk kc=0 must be issued
// BEFORE entering. 2 A ds_read_b128 + 8 B ds_read_b128 + 16 MFMA per kc.
#define GEMM512_DMA(BP)                                                         \
  {                                                                             \
    _Pragma("unroll") for (int mt = 0; mt < 2; ++mt)                            \
      _Pragma("unroll") for (int nt = 0; nt < 8; ++nt)                          \
        acc[mt][nt] = (f32x4){0.f, 0.f, 0.f, 0.f};                              \
    for (int kc = 0; kc < 16; ++kc) {                                           \
      __builtin_amdgcn_s_waitcnt(WAIT_VM0);   /* my chunk kc landed */          \
      s16x8 a0 = *(const s16x8*)(buf + ln * AST + kc * 32 + q * 8);             \
      s16x8 a1 = *(const s16x8*)(buf + (16 + ln) * AST + kc * 32 + q * 8);      \
      s16x8 bfr[8];                                                             \
      _Pragma("unroll")                                                         \
      for (int nt = 0; nt < 8; ++nt)                                            \
        bfr[nt] = *(const s16x8*)(bs + (wave * 8 + nt) * 512 + lane * 8);       \
      _Pragma("unroll")                                                         \
      for (int nt = 0; nt < 8; ++nt) {                                          \
        acc[0][nt] = MFMA_BF16(a0, bfr[nt], acc[0][nt]);                        \
        acc[1][nt] = MFMA_BF16(a1, bfr[nt], acc[1][nt]);                        \
      }                                                                         \
      __builtin_amdgcn_s_waitcnt(WAIT_LGKM0); /* bs reads retired */            \
      if (kc < 15) ISSUE_CHUNK(BP, kc + 1);                                     \
    }                                                                           \
  }

// Proven-clean base: M=32, block=256, (256,2) -> no spills (round-4 evidence).
// LDS: xs 4.5K + buf 33K + bs 32K = 69K -> 2 blocks/CU for cross-block overlap.
__global__ __launch_bounds__(256, 2) void hnn_fused(
    const float* __restrict__ x,
    const float* __restrict__ bias0,
    const float* __restrict__ bias1,
    const float* __restrict__ bias2,
    const float* __restrict__ W3,
    const u16* __restrict__ ws,
    float* __restrict__ out)
{
  const u16* p0f = ws;
  const u16* p0b = p0f + D_IN * H_DIM;
  const u16* p1f = p0b + D_IN * H_DIM;
  const u16* p1b = p1f + H_DIM * H_DIM;
  const u16* p2f = p1b + H_DIM * H_DIM;
  const u16* p2b = p2f + H_DIM * H_DIM;

  __shared__ __align__(16) u16 xs[M_TILE * XST];    // 4.5 KB
  __shared__ __align__(16) u16 buf[M_TILE * AST];   // 32.5 KB (A activations)
  __shared__ __align__(16) u16 bs[32 * 512];        // 32 KB (B stage, 8 seg/wave)

  const int tid  = threadIdx.x;
  const int wave = tid >> 6;
  const int lane = tid & 63;
  const int ln   = lane & 15;
  const int q    = lane >> 4;
  const int nwb  = wave * 128;
  const int row0 = blockIdx.x * M_TILE;

  // ---- stage x tile: 32x64 fp32 -> bf16 LDS ----
  {
    int e = tid * 8;
    int r = e >> 6, c = e & 63;
    const float4* src = (const float4*)(x + (size_t)(row0 + r) * D_IN + c);
    float4 f0 = src[0];
    float4 f1 = src[1];
    u16* dst = xs + r * XST + c;
    dst[0] = f2bf(f0.x); dst[1] = f2bf(f0.y); dst[2] = f2bf(f0.z); dst[3] = f2bf(f0.w);
    dst[4] = f2bf(f1.x); dst[5] = f2bf(f1.y); dst[6] = f2bf(f1.z); dst[7] = f2bf(f1.w);
  }
  __syncthreads();

  f32x4 acc[2][8];
  unsigned h0p[2][8][2];   // h0 bf16x2-packed, C-layout (for tanh' in bwd)
  unsigned h1p[2][8][2];
  float bias[8];

  // ================ GEMM0: z0 = x @ W0  (K=64, register-B) ================
  #pragma unroll
  for (int nt = 0; nt < 8; ++nt) bias[nt] = bias0[nwb + nt * 16 + ln];
  #pragma unroll
  for (int mt = 0; mt < 2; ++mt)
    #pragma unroll
    for (int nt = 0; nt < 8; ++nt) acc[mt][nt] = (f32x4){0.f, 0.f, 0.f, 0.f};
  {
    const u16* bpw0 = p0f + (wave << 13) + lane * 8;
    #pragma unroll
    for (int kc = 0; kc < 2; ++kc) {
      s16x8 a0 = *(const s16x8*)(xs + ln * XST + kc * 32 + q * 8);
      s16x8 a1 = *(const s16x8*)(xs + (16 + ln) * XST + kc * 32 + q * 8);
      #pragma unroll
      for (int nt = 0; nt < 8; ++nt) {
        s16x8 b = *(const s16x8*)(bpw0 + ((nt * 2 + kc) << 9));
        acc[0][nt] = MFMA_BF16(a0, b, acc[0][nt]);
        acc[1][nt] = MFMA_BF16(a1, b, acc[1][nt]);
      }
    }
  }
  ISSUE_CHUNK(p1f, 0);   // prefetch GEMM1 chunk0; overlaps epilogue VALU
  // epilogue: h0 = tanh(z0+b0) -> regs + buf
  #pragma unroll
  for (int mt = 0; mt < 2; ++mt)
    #pragma unroll
    for (int nt = 0; nt < 8; ++nt) {
      int col = nwb + nt * 16 + ln;
      u16 u[4];
      #pragma unroll
      for (int r = 0; r < 4; ++r) {
        float th = fast_tanh(acc[mt][nt][r] + bias[nt]);
        u[r] = f2bf(th);
        buf[(mt * 16 + q * 4 + r) * AST + col] = u[r];
      }
      h0p[mt][nt][0] = (unsigned)u[0] | ((unsigned)u[1] << 16);
      h0p[mt][nt][1] = (unsigned)u[2] | ((unsigned)u[3] << 16);
    }
  __syncthreads();

  // ================ GEMM1: z1 = h0 @ W1 ================
  #pragma unroll
  for (int nt = 0; nt < 8; ++nt) bias[nt] = bias1[nwb + nt * 16 + ln];
  GEMM512_DMA(p1f);
  __syncthreads();        // all waves done reading h0 (buf) + bs
  ISSUE_CHUNK(p2f, 0);    // prefetch GEMM2 chunk0; overlaps epilogue
  #pragma unroll
  for (int mt = 0; mt < 2; ++mt)
    #pragma unroll
    for (int nt = 0; nt < 8; ++nt) {
      int col = nwb + nt * 16 + ln;
      u16 u[4];
      #pragma unroll
      for (int r = 0; r < 4; ++r) {
        float th = fast_tanh(acc[mt][nt][r] + bias[nt]);
        u[r] = f2bf(th);
        buf[(mt * 16 + q * 4 + r) * AST + col] = u[r];
      }
      h1p[mt][nt][0] = (unsigned)u[0] | ((unsigned)u[1] << 16);
      h1p[mt][nt][1] = (unsigned)u[2] | ((unsigned)u[3] << 16);
    }
  __syncthreads();

  // ================ GEMM2: z2 = h1 @ W2 ; gz2 = W3*(1-h2^2) ================
  #pragma unroll
  for (int nt = 0; nt < 8; ++nt) bias[nt] = bias2[nwb + nt * 16 + ln];
  float w3v[8];
  #pragma unroll
  for (int nt = 0; nt < 8; ++nt) w3v[nt] = W3[nwb + nt * 16 + ln];
  GEMM512_DMA(p2f);
  __syncthreads();
  ISSUE_CHUNK(p2b, 0);    // prefetch GEMM3 chunk0
  #pragma unroll
  for (int mt = 0; mt < 2; ++mt)
    #pragma unroll
    for (int nt = 0; nt < 8; ++nt) {
      int col = nwb + nt * 16 + ln;
      #pragma unroll
      for (int r = 0; r < 4; ++r) {
        float th = fast_tanh(acc[mt][nt][r] + bias[nt]);
        float gz = w3v[nt] * (1.0f - th * th);
        buf[(mt * 16 + q * 4 + r) * AST + col] = f2bf(gz);
      }
    }
  __syncthreads();

  // ================ GEMM3: g1 = gz2 @ W2^T ; gz1 = g1*(1-h1^2) ================
  GEMM512_DMA(p2b);
  __syncthreads();
  ISSUE_CHUNK(p1b, 0);    // prefetch GEMM4 chunk0
  #pragma unroll
  for (int mt = 0; mt < 2; ++mt)
    #pragma unroll
    for (int nt = 0; nt < 8; ++nt) {
      int col = nwb + nt * 16 + ln;
      unsigned pa = h1p[mt][nt][0], pb = h1p[mt][nt][1];
      float hh[4] = { bfb2f(pa & 0xffffu), bfb2f(pa >> 16),
                      bfb2f(pb & 0xffffu), bfb2f(pb >> 16) };
      #pragma unroll
      for (int r = 0; r < 4; ++r) {
        float gz = acc[mt][nt][r] * (1.0f - hh[r] * hh[r]);
        buf[(mt * 16 + q * 4 + r) * AST + col] = f2bf(gz);
      }
    }
  __syncthreads();

  // ================ GEMM4: g0 = gz1 @ W1^T ; gz0 = g0*(1-h0^2) ================
  GEMM512_DMA(p1b);
  __syncthreads();
  #pragma unroll
  for (int mt = 0; mt < 2; ++mt)
    #pragma unroll
    for (int nt = 0; nt < 8; ++nt) {
      int col = nwb + nt * 16 + ln;
      unsigned pa = h0p[mt][nt][0], pb = h0p[mt][nt][1];
      float hh[4] = { bfb2f(pa & 0xffffu), bfb2f(pa >> 16),
                      bfb2f(pb & 0xffffu), bfb2f(pb >> 16) };
      #pragma unroll
      for (int r = 0; r < 4; ++r) {
        float gz = acc[mt][nt][r] * (1.0f - hh[r] * hh[r]);
        buf[(mt * 16 + q * 4 + r) * AST + col] = f2bf(gz);
      }
    }
  __syncthreads();

  // ================ GEMM5: gradH = gz0 @ W0^T (32x64), symplectic store ======
  {
    f32x4 acc5[2];
    acc5[0] = (f32x4){0.f, 0.f, 0.f, 0.f};
    acc5[1] = (f32x4){0.f, 0.f, 0.f, 0.f};
    const int mt5 = wave & 1;            // row half
    const int nb5 = (wave >> 1) * 32;    // gradH column base (0 or 32)
    const u16* bp5 = p0b + ((wave >> 1) << 14) + lane * 8;
    #pragma unroll 2
    for (int kc = 0; kc < 16; ++kc) {
      s16x8 a = *(const s16x8*)(buf + (mt5 * 16 + ln) * AST + kc * 32 + q * 8);
      #pragma unroll
      for (int nt = 0; nt < 2; ++nt) {
        s16x8 b = *(const s16x8*)(bp5 + ((nt * 16 + kc) << 9));
        acc5[nt] = MFMA_BF16(a, b, acc5[nt]);
      }
    }
    #pragma unroll
    for (int nt = 0; nt < 2; ++nt) {
      int g = nb5 + nt * 16 + ln;                 // gradH column
      int c = (g < 32) ? g + 32 : g - 32;         // out = concat(gradH[:,32:], -gradH[:,:32])
      float s = (g < 32) ? -1.0f : 1.0f;
      #pragma unroll
      for (int r = 0; r < 4; ++r) {
        int grow = row0 + mt5 * 16 + q * 4 + r;
        out[(size_t)grow * 64 + c] = s * acc5[nt][r];
      }
    }
  }
}

extern "C" void kernel_launch(void* const* d_in, const int* in_sizes, int n_in,
                              void* d_out, int out_size, void* d_ws, size_t ws_size,
                              hipStream_t stream) {
  // setup_inputs order: t, x, W0, b0, W1, b1, W2, b2, W3, b3
  const float* x  = (const float*)d_in[1];
  const float* W0 = (const float*)d_in[2];
  const float* b0 = (const float*)d_in[3];
  const float* W1 = (const float*)d_in[4];
  const float* b1 = (const float*)d_in[5];
  const float* W2 = (const float*)d_in[6];
  const float* b2 = (const float*)d_in[7];
  const float* W3 = (const float*)d_in[8];
  u16* ws = (u16*)d_ws;
  float* out = (float*)d_out;

  prep_weights<<<128, 256, 0, stream>>>(W0, W1, W2, ws);
  hnn_fused<<<65536 / M_TILE, 256, 0, stream>>>(x, b0, b1, b2, W3, ws, out);
}

// Round 8
// 284.576 us; speedup vs baseline: 1.4568x; 1.0601x over previous
//
#include <hip/hip_runtime.h>
#include <hip/hip_bf16.h>

typedef unsigned short u16;
typedef short s16x8 __attribute__((ext_vector_type(8)));
typedef float f32x4 __attribute__((ext_vector_type(4)));

#define MFMA_BF16(a, b, c) __builtin_amdgcn_mfma_f32_16x16x32_bf16((a), (b), (c), 0, 0, 0)

static constexpr int D_IN   = 64;
static constexpr int H_DIM  = 512;
static constexpr int M_TILE = 32;
static constexpr int AST    = 520;  // LDS row stride (bf16)
static constexpr int XST    = 72;   // LDS row stride for x tile

// s_waitcnt immediates (gfx9 encoding): vmcnt[3:0]|exp[6:4]|lgkm[11:8]|vmcnt-hi[15:14]
#define WAIT_VM4   0x0F74  // vmcnt(4): oldest (outstanding-4) loads done; lgkm/exp free
#define WAIT_LGKM0 0xC07F  // lgkmcnt(0); vm/exp free

__device__ __forceinline__ u16 f2bf(float f) {
  unsigned u = __builtin_bit_cast(unsigned, f);
  u += 0x7fffu + ((u >> 16) & 1u);   // RNE
  return (u16)(u >> 16);
}
__device__ __forceinline__ float bfb2f(unsigned bits16) {
  return __builtin_bit_cast(float, bits16 << 16);
}
__device__ __forceinline__ float fast_tanh(float x) {
  float e = __expf(2.0f * x);
  return 1.0f - 2.0f * __builtin_amdgcn_rcpf(e + 1.0f);
}
// async global->LDS DMA, 16B/lane: lds dest = wave-uniform base + lane*16
__device__ __forceinline__ void dma16(const u16* g, u16* l) {
  __builtin_amdgcn_global_load_lds(
      (const __attribute__((address_space(1))) unsigned int*)g,
      (__attribute__((address_space(3))) unsigned int*)l, 16, 0, 0);
}

// ---- prep: fp32 weights -> bf16, packed in MFMA-B-fragment order ----
// For each (ntg = 16-col tile, kc = 32-wide K chunk): 512 elems stored as
// lane*8 contiguous, lane=(q*16+ln), elem j -> B[k=kc*32+q*8+j][n=ntg*16+ln].
// ws layout (bf16): p0f[64x512] p0b[512x64] p1f p1b p2f p2b  (~2.2MB)
__global__ void prep_weights(const float* __restrict__ W0,
                             const float* __restrict__ W1,
                             const float* __restrict__ W2,
                             u16* __restrict__ ws) {
  u16* p0f = ws;                       // fwd W0: K=64,  N=512
  u16* p0b = p0f + D_IN * H_DIM;       // bwd W0^T: K=512, N=64
  u16* p1f = p0b + D_IN * H_DIM;
  u16* p1b = p1f + H_DIM * H_DIM;
  u16* p2f = p1b + H_DIM * H_DIM;
  u16* p2b = p2f + H_DIM * H_DIM;

  int t = blockIdx.x * 256 + threadIdx.x;   // 32768 threads total
  int lane = t & 63;
  int kc   = (t >> 6) & 15;
  int ntg  = t >> 10;                       // 0..31
  int ln = lane & 15, q = lane >> 4;
  int n = ntg * 16 + ln;
  int k = kc * 32 + q * 8;

  #pragma unroll
  for (int j = 0; j < 8; ++j) {
    p1f[t * 8 + j] = f2bf(W1[(k + j) * 512 + n]);
    p2f[t * 8 + j] = f2bf(W2[(k + j) * 512 + n]);
    p1b[t * 8 + j] = f2bf(W1[n * 512 + (k + j)]);
    p2b[t * 8 + j] = f2bf(W2[n * 512 + (k + j)]);
  }
  if (kc < 2) {  // W0 fwd: K=64 -> kc in {0,1}, ntg 0..31
    int t0 = (ntg * 2 + kc) * 64 + lane;
    #pragma unroll
    for (int j = 0; j < 8; ++j)
      p0f[t0 * 8 + j] = f2bf(W0[(k + j) * 512 + n]);   // W0[k][n], k<64
  }
  if (ntg < 4) { // W0 bwd: N=64 -> ntg 0..3, kc 0..15
    int t0 = (ntg * 16 + kc) * 64 + lane;
    #pragma unroll
    for (int j = 0; j < 8; ++j)
      p0b[t0 * 8 + j] = f2bf(W0[n * 512 + (k + j)]);   // W0[n][k], n<64
  }
}

// stage HALF-chunk (4 ntg segments, 4KB) of chunk KC into wave-private buffer
// HALF (0/1). Wave's bs region: 8KB = 2 buffers x 4 segs x 512 elems.
#define ISSUE_HALF(BP, KC, HALF)                                                \
  {                                                                             \
    const u16* _src = (BP) +                                                    \
        ((size_t)(wave * 8 + (HALF) * 4) * 16 + (KC)) * 512 + lane * 8;         \
    u16* _dst = &bs[wave * 4096 + (HALF) * 2048];                               \
    _Pragma("unroll")                                                           \
    for (int s = 0; s < 4; ++s)                                                 \
      dma16(_src + s * (16 * 512), _dst + s * 512);                             \
  }

// 512-wide GEMM K-loop, double-buffered DMA halves, vmcnt(4) (never 0):
// two half-chunks (8 loads) in flight at all times; each wait only covers
// (DMA latency - one half-step of work). No barriers inside (bs wave-private;
// waves de-phase). Both halves of chunk 0 must be issued BEFORE entering.
#define GEMM512_DMA(BP)                                                         \
  {                                                                             \
    _Pragma("unroll") for (int mt = 0; mt < 2; ++mt)                            \
      _Pragma("unroll") for (int nt = 0; nt < 8; ++nt)                          \
        acc[mt][nt] = (f32x4){0.f, 0.f, 0.f, 0.f};                              \
    for (int kc = 0; kc < 16; ++kc) {                                           \
      __builtin_amdgcn_s_waitcnt(WAIT_VM4);   /* (kc,h0) landed, (kc,h1) fly */ \
      s16x8 a0 = *(const s16x8*)(buf + ln * AST + kc * 32 + q * 8);             \
      s16x8 a1 = *(const s16x8*)(buf + (16 + ln) * AST + kc * 32 + q * 8);      \
      s16x8 b0[4];                                                              \
      _Pragma("unroll")                                                         \
      for (int s = 0; s < 4; ++s)                                               \
        b0[s] = *(const s16x8*)(bs + wave * 4096 + s * 512 + lane * 8);         \
      _Pragma("unroll")                                                         \
      for (int s = 0; s < 4; ++s) {                                             \
        acc[0][s] = MFMA_BF16(a0, b0[s], acc[0][s]);                            \
        acc[1][s] = MFMA_BF16(a1, b0[s], acc[1][s]);                            \
      }                                                                         \
      __builtin_amdgcn_s_waitcnt(WAIT_LGKM0); /* buf0 reads retired */          \
      if (kc < 15) ISSUE_HALF(BP, kc + 1, 0); /* refill buf0 */                 \
      __builtin_amdgcn_s_waitcnt(WAIT_VM4);   /* (kc,h1) landed */              \
      s16x8 b1[4];                                                              \
      _Pragma("unroll")                                                         \
      for (int s = 0; s < 4; ++s)                                               \
        b1[s] = *(const s16x8*)(bs + wave * 4096 + 2048 + s * 512 + lane * 8);  \
      _Pragma("unroll")                                                         \
      for (int s = 0; s < 4; ++s) {                                             \
        acc[0][4 + s] = MFMA_BF16(a0, b1[s], acc[0][4 + s]);                    \
        acc[1][4 + s] = MFMA_BF16(a1, b1[s], acc[1][4 + s]);                    \
      }                                                                         \
      __builtin_amdgcn_s_waitcnt(WAIT_LGKM0); /* buf1 reads retired */          \
      if (kc < 15) ISSUE_HALF(BP, kc + 1, 1); /* refill buf1 */                 \
    }                                                                           \
  }

// Proven-clean base: M=32, block=256, (256,2) -> 128 VGPR, no spills.
// LDS: xs 4.5K + buf 33K + bs 32K = 69K -> 2 blocks/CU.
__global__ __launch_bounds__(256, 2) void hnn_fused(
    const float* __restrict__ x,
    const float* __restrict__ bias0,
    const float* __restrict__ bias1,
    const float* __restrict__ bias2,
    const float* __restrict__ W3,
    const u16* __restrict__ ws,
    float* __restrict__ out)
{
  const u16* p0f = ws;
  const u16* p0b = p0f + D_IN * H_DIM;
  const u16* p1f = p0b + D_IN * H_DIM;
  const u16* p1b = p1f + H_DIM * H_DIM;
  const u16* p2f = p1b + H_DIM * H_DIM;
  const u16* p2b = p2f + H_DIM * H_DIM;

  __shared__ __align__(16) u16 xs[M_TILE * XST];    // 4.5 KB
  __shared__ __align__(16) u16 buf[M_TILE * AST];   // 32.5 KB (A activations)
  __shared__ __align__(16) u16 bs[32 * 512];        // 32 KB (B stage: 2x4KB/wave)

  const int tid  = threadIdx.x;
  const int wave = tid >> 6;
  const int lane = tid & 63;
  const int ln   = lane & 15;
  const int q    = lane >> 4;
  const int nwb  = wave * 128;
  const int row0 = blockIdx.x * M_TILE;

  // ---- stage x tile: 32x64 fp32 -> bf16 LDS ----
  {
    int e = tid * 8;
    int r = e >> 6, c = e & 63;
    const float4* src = (const float4*)(x + (size_t)(row0 + r) * D_IN + c);
    float4 f0 = src[0];
    float4 f1 = src[1];
    u16* dst = xs + r * XST + c;
    dst[0] = f2bf(f0.x); dst[1] = f2bf(f0.y); dst[2] = f2bf(f0.z); dst[3] = f2bf(f0.w);
    dst[4] = f2bf(f1.x); dst[5] = f2bf(f1.y); dst[6] = f2bf(f1.z); dst[7] = f2bf(f1.w);
  }
  __syncthreads();

  f32x4 acc[2][8];
  unsigned h0p[2][8][2];   // h0 bf16x2-packed, C-layout (for tanh' in bwd)
  unsigned h1p[2][8][2];
  float bias[8];

  // ================ GEMM0: z0 = x @ W0  (K=64, register-B) ================
  #pragma unroll
  for (int nt = 0; nt < 8; ++nt) bias[nt] = bias0[nwb + nt * 16 + ln];
  #pragma unroll
  for (int mt = 0; mt < 2; ++mt)
    #pragma unroll
    for (int nt = 0; nt < 8; ++nt) acc[mt][nt] = (f32x4){0.f, 0.f, 0.f, 0.f};
  {
    const u16* bpw0 = p0f + (wave << 13) + lane * 8;
    #pragma unroll
    for (int kc = 0; kc < 2; ++kc) {
      s16x8 a0 = *(const s16x8*)(xs + ln * XST + kc * 32 + q * 8);
      s16x8 a1 = *(const s16x8*)(xs + (16 + ln) * XST + kc * 32 + q * 8);
      #pragma unroll
      for (int nt = 0; nt < 8; ++nt) {
        s16x8 b = *(const s16x8*)(bpw0 + ((nt * 2 + kc) << 9));
        acc[0][nt] = MFMA_BF16(a0, b, acc[0][nt]);
        acc[1][nt] = MFMA_BF16(a1, b, acc[1][nt]);
      }
    }
  }
  ISSUE_HALF(p1f, 0, 0);  // prefetch GEMM1 chunk0 (both halves); overlaps epilogue
  ISSUE_HALF(p1f, 0, 1);
  // epilogue: h0 = tanh(z0+b0) -> regs + buf
  #pragma unroll
  for (int mt = 0; mt < 2; ++mt)
    #pragma unroll
    for (int nt = 0; nt < 8; ++nt) {
      int col = nwb + nt * 16 + ln;
      u16 u[4];
      #pragma unroll
      for (int r = 0; r < 4; ++r) {
        float th = fast_tanh(acc[mt][nt][r] + bias[nt]);
        u[r] = f2bf(th);
        buf[(mt * 16 + q * 4 + r) * AST + col] = u[r];
      }
      h0p[mt][nt][0] = (unsigned)u[0] | ((unsigned)u[1] << 16);
      h0p[mt][nt][1] = (unsigned)u[2] | ((unsigned)u[3] << 16);
    }
  __syncthreads();

  // ================ GEMM1: z1 = h0 @ W1 ================
  #pragma unroll
  for (int nt = 0; nt < 8; ++nt) bias[nt] = bias1[nwb + nt * 16 + ln];
  GEMM512_DMA(p1f);
  __syncthreads();        // all waves done reading h0 (buf)
  ISSUE_HALF(p2f, 0, 0);  // prefetch GEMM2 chunk0
  ISSUE_HALF(p2f, 0, 1);
  #pragma unroll
  for (int mt = 0; mt < 2; ++mt)
    #pragma unroll
    for (int nt = 0; nt < 8; ++nt) {
      int col = nwb + nt * 16 + ln;
      u16 u[4];
      #pragma unroll
      for (int r = 0; r < 4; ++r) {
        float th = fast_tanh(acc[mt][nt][r] + bias[nt]);
        u[r] = f2bf(th);
        buf[(mt * 16 + q * 4 + r) * AST + col] = u[r];
      }
      h1p[mt][nt][0] = (unsigned)u[0] | ((unsigned)u[1] << 16);
      h1p[mt][nt][1] = (unsigned)u[2] | ((unsigned)u[3] << 16);
    }
  __syncthreads();

  // ================ GEMM2: z2 = h1 @ W2 ; gz2 = W3*(1-h2^2) ================
  #pragma unroll
  for (int nt = 0; nt < 8; ++nt) bias[nt] = bias2[nwb + nt * 16 + ln];
  float w3v[8];
  #pragma unroll
  for (int nt = 0; nt < 8; ++nt) w3v[nt] = W3[nwb + nt * 16 + ln];
  GEMM512_DMA(p2f);
  __syncthreads();
  ISSUE_HALF(p2b, 0, 0);  // prefetch GEMM3 chunk0
  ISSUE_HALF(p2b, 0, 1);
  #pragma unroll
  for (int mt = 0; mt < 2; ++mt)
    #pragma unroll
    for (int nt = 0; nt < 8; ++nt) {
      int col = nwb + nt * 16 + ln;
      #pragma unroll
      for (int r = 0; r < 4; ++r) {
        float th = fast_tanh(acc[mt][nt][r] + bias[nt]);
        float gz = w3v[nt] * (1.0f - th * th);
        buf[(mt * 16 + q * 4 + r) * AST + col] = f2bf(gz);
      }
    }
  __syncthreads();

  // ================ GEMM3: g1 = gz2 @ W2^T ; gz1 = g1*(1-h1^2) ================
  GEMM512_DMA(p2b);
  __syncthreads();
  ISSUE_HALF(p1b, 0, 0);  // prefetch GEMM4 chunk0
  ISSUE_HALF(p1b, 0, 1);
  #pragma unroll
  for (int mt = 0; mt < 2; ++mt)
    #pragma unroll
    for (int nt = 0; nt < 8; ++nt) {
      int col = nwb + nt * 16 + ln;
      unsigned pa = h1p[mt][nt][0], pb = h1p[mt][nt][1];
      float hh[4] = { bfb2f(pa & 0xffffu), bfb2f(pa >> 16),
                      bfb2f(pb & 0xffffu), bfb2f(pb >> 16) };
      #pragma unroll
      for (int r = 0; r < 4; ++r) {
        float gz = acc[mt][nt][r] * (1.0f - hh[r] * hh[r]);
        buf[(mt * 16 + q * 4 + r) * AST + col] = f2bf(gz);
      }
    }
  __syncthreads();

  // ================ GEMM4: g0 = gz1 @ W1^T ; gz0 = g0*(1-h0^2) ================
  GEMM512_DMA(p1b);
  __syncthreads();
  #pragma unroll
  for (int mt = 0; mt < 2; ++mt)
    #pragma unroll
    for (int nt = 0; nt < 8; ++nt) {
      int col = nwb + nt * 16 + ln;
      unsigned pa = h0p[mt][nt][0], pb = h0p[mt][nt][1];
      float hh[4] = { bfb2f(pa & 0xffffu), bfb2f(pa >> 16),
                      bfb2f(pb & 0xffffu), bfb2f(pb >> 16) };
      #pragma unroll
      for (int r = 0; r < 4; ++r) {
        float gz = acc[mt][nt][r] * (1.0f - hh[r] * hh[r]);
        buf[(mt * 16 + q * 4 + r) * AST + col] = f2bf(gz);
      }
    }
  __syncthreads();

  // ================ GEMM5: gradH = gz0 @ W0^T (32x64), symplectic store ======
  {
    f32x4 acc5[2];
    acc5[0] = (f32x4){0.f, 0.f, 0.f, 0.f};
    acc5[1] = (f32x4){0.f, 0.f, 0.f, 0.f};
    const int mt5 = wave & 1;            // row half
    const int nb5 = (wave >> 1) * 32;    // gradH column base (0 or 32)
    const u16* bp5 = p0b + ((wave >> 1) << 14) + lane * 8;
    #pragma unroll 2
    for (int kc = 0; kc < 16; ++kc) {
      s16x8 a = *(const s16x8*)(buf + (mt5 * 16 + ln) * AST + kc * 32 + q * 8);
      #pragma unroll
      for (int nt = 0; nt < 2; ++nt) {
        s16x8 b = *(const s16x8*)(bp5 + ((nt * 16 + kc) << 9));
        acc5[nt] = MFMA_BF16(a, b, acc5[nt]);
      }
    }
    #pragma unroll
    for (int nt = 0; nt < 2; ++nt) {
      int g = nb5 + nt * 16 + ln;                 // gradH column
      int c = (g < 32) ? g + 32 : g - 32;         // out = concat(gradH[:,32:], -gradH[:,:32])
      float s = (g < 32) ? -1.0f : 1.0f;
      #pragma unroll
      for (int r = 0; r < 4; ++r) {
        int grow = row0 + mt5 * 16 + q * 4 + r;
        out[(size_t)grow * 64 + c] = s * acc5[nt][r];
      }
    }
  }
}

extern "C" void kernel_launch(void* const* d_in, const int* in_sizes, int n_in,
                              void* d_out, int out_size, void* d_ws, size_t ws_size,
                              hipStream_t stream) {
  // setup_inputs order: t, x, W0, b0, W1, b1, W2, b2, W3, b3
  const float* x  = (const float*)d_in[1];
  const float* W0 = (const float*)d_in[2];
  const float* b0 = (const float*)d_in[3];
  const float* W1 = (const float*)d_in[4];
  const float* b1 = (const float*)d_in[5];
  const float* W2 = (const float*)d_in[6];
  const float* b2 = (const float*)d_in[7];
  const float* W3 = (const float*)d_in[8];
  u16* ws = (u16*)d_ws;
  float* out = (float*)d_out;

  prep_weights<<<128, 256, 0, stream>>>(W0, W1, W2, ws);
  hnn_fused<<<65536 / M_TILE, 256, 0, stream>>>(x, b0, b1, b2, W3, ws, out);
}

// Round 9
// 270.331 us; speedup vs baseline: 1.5336x; 1.0527x over previous
//
#include <hip/hip_runtime.h>
#include <hip/hip_bf16.h>

typedef unsigned short u16;
typedef short s16x8 __attribute__((ext_vector_type(8)));
typedef float f32x4 __attribute__((ext_vector_type(4)));

#define MFMA_BF16(a, b, c) __builtin_amdgcn_mfma_f32_16x16x32_bf16((a), (b), (c), 0, 0, 0)

static constexpr int D_IN   = 64;
static constexpr int H_DIM  = 512;
static constexpr int M_TILE = 32;
static constexpr int AST    = 520;  // LDS row stride (bf16)
static constexpr int XST    = 72;   // LDS row stride for x tile

// s_waitcnt immediates (gfx9): vmcnt[3:0]|exp[6:4]|lgkm[11:8]|vmcnt-hi[15:14]
#define WAIT_VM8   0x0F78  // vmcnt(8): 8 newest may fly; lgkm/exp free
#define WAIT_VM0   0x0F70  // vmcnt(0)
#define WAIT_LGKM0 0xC07F  // lgkmcnt(0); vm/exp free

__device__ __forceinline__ u16 f2bf(float f) {
  unsigned u = __builtin_bit_cast(unsigned, f);
  u += 0x7fffu + ((u >> 16) & 1u);   // RNE
  return (u16)(u >> 16);
}
__device__ __forceinline__ float bfb2f(unsigned bits16) {
  return __builtin_bit_cast(float, bits16 << 16);
}
__device__ __forceinline__ float fast_tanh(float x) {
  float e = __expf(2.0f * x);
  return 1.0f - 2.0f * __builtin_amdgcn_rcpf(e + 1.0f);
}
// async global->LDS DMA, 16B/lane: lds dest = wave-uniform base + lane*16
__device__ __forceinline__ void dma16(const u16* g, u16* l) {
  __builtin_amdgcn_global_load_lds(
      (const __attribute__((address_space(1))) unsigned int*)g,
      (__attribute__((address_space(3))) unsigned int*)l, 16, 0, 0);
}

// ---- prep: fp32 weights -> bf16, packed in MFMA-B-fragment order ----
// For each (ntg = 16-col tile, kc = 32-wide K chunk): 512 elems stored as
// lane*8 contiguous, lane=(q*16+ln), elem j -> B[k=kc*32+q*8+j][n=ntg*16+ln].
// ws layout (bf16): p0f[64x512] p0b[512x64] p1f p1b p2f p2b  (~2.2MB)
__global__ void prep_weights(const float* __restrict__ W0,
                             const float* __restrict__ W1,
                             const float* __restrict__ W2,
                             u16* __restrict__ ws) {
  u16* p0f = ws;                       // fwd W0: K=64,  N=512
  u16* p0b = p0f + D_IN * H_DIM;       // bwd W0^T: K=512, N=64
  u16* p1f = p0b + D_IN * H_DIM;
  u16* p1b = p1f + H_DIM * H_DIM;
  u16* p2f = p1b + H_DIM * H_DIM;
  u16* p2b = p2f + H_DIM * H_DIM;

  int t = blockIdx.x * 256 + threadIdx.x;   // 32768 threads total
  int lane = t & 63;
  int kc   = (t >> 6) & 15;
  int ntg  = t >> 10;                       // 0..31
  int ln = lane & 15, q = lane >> 4;
  int n = ntg * 16 + ln;
  int k = kc * 32 + q * 8;

  #pragma unroll
  for (int j = 0; j < 8; ++j) {
    p1f[t * 8 + j] = f2bf(W1[(k + j) * 512 + n]);
    p2f[t * 8 + j] = f2bf(W2[(k + j) * 512 + n]);
    p1b[t * 8 + j] = f2bf(W1[n * 512 + (k + j)]);
    p2b[t * 8 + j] = f2bf(W2[n * 512 + (k + j)]);
  }
  if (kc < 2) {  // W0 fwd: K=64 -> kc in {0,1}, ntg 0..31
    int t0 = (ntg * 2 + kc) * 64 + lane;
    #pragma unroll
    for (int j = 0; j < 8; ++j)
      p0f[t0 * 8 + j] = f2bf(W0[(k + j) * 512 + n]);   // W0[k][n], k<64
  }
  if (ntg < 4) { // W0 bwd: N=64 -> ntg 0..3, kc 0..15
    int t0 = (ntg * 16 + kc) * 64 + lane;
    #pragma unroll
    for (int j = 0; j < 8; ++j)
      p0b[t0 * 8 + j] = f2bf(W0[n * 512 + (k + j)]);   // W0[n][k], n<64
  }
}

// DMA tiles 0-3 of chunk KC into wave-private buffer BUFI (even/odd kc).
#define ISSUE_DMA4(BP, KC, BUFI)                                                \
  {                                                                             \
    const u16* _src = (BP) + ((size_t)(wave * 8) * 16 + (KC)) * 512 + lane * 8; \
    u16* _dst = &bs[wave * 4096 + (BUFI) * 2048];                               \
    _Pragma("unroll")                                                           \
    for (int s = 0; s < 4; ++s)                                                 \
      dma16(_src + s * (16 * 512), _dst + s * 512);                             \
  }
// Register-load tiles 4-7 of chunk KC into BR[4] (VGPRs, bypasses LDS).
#define ISSUE_REG4(BP, KC, BR)                                                  \
  {                                                                             \
    const u16* _sr = (BP) +                                                     \
        ((size_t)(wave * 8 + 4) * 16 + (KC)) * 512 + lane * 8;                  \
    _Pragma("unroll")                                                           \
    for (int s = 0; s < 4; ++s)                                                 \
      (BR)[s] = *(const s16x8*)(_sr + s * (16 * 512));                          \
  }
// Prologue: queue order D(0),R(0),D(1),R(1) -> every in-loop wait is vmcnt(8).
#define HYB_PROLOGUE(BP)                                                        \
  { ISSUE_DMA4(BP, 0, 0); ISSUE_REG4(BP, 0, bregA);                             \
    ISSUE_DMA4(BP, 1, 1); ISSUE_REG4(BP, 1, bregB); }

// Hybrid 512-wide GEMM K-loop (2-unrolled): tiles 0-3 via DMA->LDS (LDS pipe),
// tiles 4-7 via VGPR loads (VMEM pipe) -> LDS traffic 18KB->10KB per kc.
// Steady-state queue = {D(k),R(k),D(k+1),R(k+1)}; wait vmcnt(8) leaves the
// newer pair in flight (never drains to 0 except the last iteration).
// No barriers inside (bs wave-private; waves de-phase). HYB_PROLOGUE first.
#define GEMM512_HYB(BP)                                                         \
  {                                                                             \
    _Pragma("unroll") for (int mt = 0; mt < 2; ++mt)                            \
      _Pragma("unroll") for (int nt = 0; nt < 8; ++nt)                          \
        acc[mt][nt] = (f32x4){0.f, 0.f, 0.f, 0.f};                              \
    for (int kc2 = 0; kc2 < 8; ++kc2) {                                         \
      const int e = kc2 * 2;                                                    \
      __builtin_amdgcn_s_waitcnt(WAIT_VM8);   /* D(e),R(e) landed */            \
      {                                                                         \
        s16x8 a0 = *(const s16x8*)(buf + ln * AST + e * 32 + q * 8);            \
        s16x8 a1 = *(const s16x8*)(buf + (16 + ln) * AST + e * 32 + q * 8);     \
        s16x8 bl[4];                                                            \
        _Pragma("unroll")                                                       \
        for (int s = 0; s < 4; ++s)                                             \
          bl[s] = *(const s16x8*)(bs + wave * 4096 + s * 512 + lane * 8);       \
        _Pragma("unroll")                                                       \
        for (int s = 0; s < 4; ++s) {                                           \
          acc[0][s] = MFMA_BF16(a0, bl[s], acc[0][s]);                          \
          acc[1][s] = MFMA_BF16(a1, bl[s], acc[1][s]);                          \
          acc[0][4 + s] = MFMA_BF16(a0, bregA[s], acc[0][4 + s]);               \
          acc[1][4 + s] = MFMA_BF16(a1, bregA[s], acc[1][4 + s]);               \
        }                                                                       \
        __builtin_amdgcn_s_waitcnt(WAIT_LGKM0);                                 \
        if (kc2 < 7) { ISSUE_DMA4(BP, e + 2, 0); ISSUE_REG4(BP, e + 2, bregA); }\
      }                                                                         \
      const int o = e + 1;                                                      \
      if (kc2 == 7) __builtin_amdgcn_s_waitcnt(WAIT_VM0);   /* last pair */     \
      else          __builtin_amdgcn_s_waitcnt(WAIT_VM8);   /* D(o),R(o) */     \
      {                                                                         \
        s16x8 a0 = *(const s16x8*)(buf + ln * AST + o * 32 + q * 8);            \
        s16x8 a1 = *(const s16x8*)(buf + (16 + ln) * AST + o * 32 + q * 8);     \
        s16x8 bl[4];                                                            \
        _Pragma("unroll")                                                       \
        for (int s = 0; s < 4; ++s)                                             \
          bl[s] = *(const s16x8*)(bs + wave * 4096 + 2048 + s * 512 + lane * 8);\
        _Pragma("unroll")                                                       \
        for (int s = 0; s < 4; ++s) {                                           \
          acc[0][s] = MFMA_BF16(a0, bl[s], acc[0][s]);                          \
          acc[1][s] = MFMA_BF16(a1, bl[s], acc[1][s]);                          \
          acc[0][4 + s] = MFMA_BF16(a0, bregB[s], acc[0][4 + s]);               \
          acc[1][4 + s] = MFMA_BF16(a1, bregB[s], acc[1][4 + s]);               \
        }                                                                       \
        __builtin_amdgcn_s_waitcnt(WAIT_LGKM0);                                 \
        if (kc2 < 7) { ISSUE_DMA4(BP, o + 2, 1); ISSUE_REG4(BP, o + 2, bregB); }\
      }                                                                         \
    }                                                                           \
  }

// Proven-clean base: M=32, block=256, (256,2). LDS 69K -> 2 blocks/CU.
__global__ __launch_bounds__(256, 2) void hnn_fused(
    const float* __restrict__ x,
    const float* __restrict__ bias0,
    const float* __restrict__ bias1,
    const float* __restrict__ bias2,
    const float* __restrict__ W3,
    const u16* __restrict__ ws,
    float* __restrict__ out)
{
  const u16* p0f = ws;
  const u16* p0b = p0f + D_IN * H_DIM;
  const u16* p1f = p0b + D_IN * H_DIM;
  const u16* p1b = p1f + H_DIM * H_DIM;
  const u16* p2f = p1b + H_DIM * H_DIM;
  const u16* p2b = p2f + H_DIM * H_DIM;

  __shared__ __align__(16) u16 xs[M_TILE * XST];    // 4.5 KB
  __shared__ __align__(16) u16 buf[M_TILE * AST];   // 32.5 KB (A activations)
  __shared__ __align__(16) u16 bs[32 * 512];        // 32 KB (B stage: 2x4KB/wave)

  const int tid  = threadIdx.x;
  const int wave = tid >> 6;
  const int lane = tid & 63;
  const int ln   = lane & 15;
  const int q    = lane >> 4;
  const int nwb  = wave * 128;
  const int row0 = blockIdx.x * M_TILE;

  // ---- stage x tile: 32x64 fp32 -> bf16 LDS ----
  {
    int e = tid * 8;
    int r = e >> 6, c = e & 63;
    const float4* src = (const float4*)(x + (size_t)(row0 + r) * D_IN + c);
    float4 f0 = src[0];
    float4 f1 = src[1];
    u16* dst = xs + r * XST + c;
    dst[0] = f2bf(f0.x); dst[1] = f2bf(f0.y); dst[2] = f2bf(f0.z); dst[3] = f2bf(f0.w);
    dst[4] = f2bf(f1.x); dst[5] = f2bf(f1.y); dst[6] = f2bf(f1.z); dst[7] = f2bf(f1.w);
  }
  __syncthreads();

  f32x4 acc[2][8];
  s16x8 bregA[4], bregB[4];   // register-path B double buffer
  unsigned h0p[2][8][2];      // h0 bf16x2-packed, C-layout (for tanh' in bwd)
  unsigned h1p[2][8][2];
  float bias[8];

  // ================ GEMM0: z0 = x @ W0  (K=64, register-B) ================
  #pragma unroll
  for (int nt = 0; nt < 8; ++nt) bias[nt] = bias0[nwb + nt * 16 + ln];
  #pragma unroll
  for (int mt = 0; mt < 2; ++mt)
    #pragma unroll
    for (int nt = 0; nt < 8; ++nt) acc[mt][nt] = (f32x4){0.f, 0.f, 0.f, 0.f};
  {
    const u16* bpw0 = p0f + (wave << 13) + lane * 8;
    #pragma unroll
    for (int kc = 0; kc < 2; ++kc) {
      s16x8 a0 = *(const s16x8*)(xs + ln * XST + kc * 32 + q * 8);
      s16x8 a1 = *(const s16x8*)(xs + (16 + ln) * XST + kc * 32 + q * 8);
      #pragma unroll
      for (int nt = 0; nt < 8; ++nt) {
        s16x8 b = *(const s16x8*)(bpw0 + ((nt * 2 + kc) << 9));
        acc[0][nt] = MFMA_BF16(a0, b, acc[0][nt]);
        acc[1][nt] = MFMA_BF16(a1, b, acc[1][nt]);
      }
    }
  }
  HYB_PROLOGUE(p1f);  // prefetch GEMM1 chunks 0,1; overlaps epilogue
  // epilogue: h0 = tanh(z0+b0) -> regs + buf
  #pragma unroll
  for (int mt = 0; mt < 2; ++mt)
    #pragma unroll
    for (int nt = 0; nt < 8; ++nt) {
      int col = nwb + nt * 16 + ln;
      u16 u[4];
      #pragma unroll
      for (int r = 0; r < 4; ++r) {
        float th = fast_tanh(acc[mt][nt][r] + bias[nt]);
        u[r] = f2bf(th);
        buf[(mt * 16 + q * 4 + r) * AST + col] = u[r];
      }
      h0p[mt][nt][0] = (unsigned)u[0] | ((unsigned)u[1] << 16);
      h0p[mt][nt][1] = (unsigned)u[2] | ((unsigned)u[3] << 16);
    }
  __syncthreads();

  // ================ GEMM1: z1 = h0 @ W1 ================
  #pragma unroll
  for (int nt = 0; nt < 8; ++nt) bias[nt] = bias1[nwb + nt * 16 + ln];
  GEMM512_HYB(p1f);
  __syncthreads();        // all waves done reading h0 (buf)
  HYB_PROLOGUE(p2f);      // prefetch GEMM2
  #pragma unroll
  for (int mt = 0; mt < 2; ++mt)
    #pragma unroll
    for (int nt = 0; nt < 8; ++nt) {
      int col = nwb + nt * 16 + ln;
      u16 u[4];
      #pragma unroll
      for (int r = 0; r < 4; ++r) {
        float th = fast_tanh(acc[mt][nt][r] + bias[nt]);
        u[r] = f2bf(th);
        buf[(mt * 16 + q * 4 + r) * AST + col] = u[r];
      }
      h1p[mt][nt][0] = (unsigned)u[0] | ((unsigned)u[1] << 16);
      h1p[mt][nt][1] = (unsigned)u[2] | ((unsigned)u[3] << 16);
    }
  __syncthreads();

  // ================ GEMM2: z2 = h1 @ W2 ; gz2 = W3*(1-h2^2) ================
  #pragma unroll
  for (int nt = 0; nt < 8; ++nt) bias[nt] = bias2[nwb + nt * 16 + ln];
  float w3v[8];
  #pragma unroll
  for (int nt = 0; nt < 8; ++nt) w3v[nt] = W3[nwb + nt * 16 + ln];
  GEMM512_HYB(p2f);
  __syncthreads();
  HYB_PROLOGUE(p2b);      // prefetch GEMM3
  #pragma unroll
  for (int mt = 0; mt < 2; ++mt)
    #pragma unroll
    for (int nt = 0; nt < 8; ++nt) {
      int col = nwb + nt * 16 + ln;
      #pragma unroll
      for (int r = 0; r < 4; ++r) {
        float th = fast_tanh(acc[mt][nt][r] + bias[nt]);
        float gz = w3v[nt] * (1.0f - th * th);
        buf[(mt * 16 + q * 4 + r) * AST + col] = f2bf(gz);
      }
    }
  __syncthreads();

  // ================ GEMM3: g1 = gz2 @ W2^T ; gz1 = g1*(1-h1^2) ================
  GEMM512_HYB(p2b);
  __syncthreads();
  HYB_PROLOGUE(p1b);      // prefetch GEMM4
  #pragma unroll
  for (int mt = 0; mt < 2; ++mt)
    #pragma unroll
    for (int nt = 0; nt < 8; ++nt) {
      int col = nwb + nt * 16 + ln;
      unsigned pa = h1p[mt][nt][0], pb = h1p[mt][nt][1];
      float hh[4] = { bfb2f(pa & 0xffffu), bfb2f(pa >> 16),
                      bfb2f(pb & 0xffffu), bfb2f(pb >> 16) };
      #pragma unroll
      for (int r = 0; r < 4; ++r) {
        float gz = acc[mt][nt][r] * (1.0f - hh[r] * hh[r]);
        buf[(mt * 16 + q * 4 + r) * AST + col] = f2bf(gz);
      }
    }
  __syncthreads();

  // ================ GEMM4: g0 = gz1 @ W1^T ; gz0 = g0*(1-h0^2) ================
  GEMM512_HYB(p1b);
  __syncthreads();
  #pragma unroll
  for (int mt = 0; mt < 2; ++mt)
    #pragma unroll
    for (int nt = 0; nt < 8; ++nt) {
      int col = nwb + nt * 16 + ln;
      unsigned pa = h0p[mt][nt][0], pb = h0p[mt][nt][1];
      float hh[4] = { bfb2f(pa & 0xffffu), bfb2f(pa >> 16),
                      bfb2f(pb & 0xffffu), bfb2f(pb >> 16) };
      #pragma unroll
      for (int r = 0; r < 4; ++r) {
        float gz = acc[mt][nt][r] * (1.0f - hh[r] * hh[r]);
        buf[(mt * 16 + q * 4 + r) * AST + col] = f2bf(gz);
      }
    }
  __syncthreads();

  // ================ GEMM5: gradH = gz0 @ W0^T (32x64), symplectic store ======
  {
    f32x4 acc5[2];
    acc5[0] = (f32x4){0.f, 0.f, 0.f, 0.f};
    acc5[1] = (f32x4){0.f, 0.f, 0.f, 0.f};
    const int mt5 = wave & 1;            // row half
    const int nb5 = (wave >> 1) * 32;    // gradH column base (0 or 32)
    const u16* bp5 = p0b + ((wave >> 1) << 14) + lane * 8;
    #pragma unroll 2
    for (int kc = 0; kc < 16; ++kc) {
      s16x8 a = *(const s16x8*)(buf + (mt5 * 16 + ln) * AST + kc * 32 + q * 8);
      #pragma unroll
      for (int nt = 0; nt < 2; ++nt) {
        s16x8 b = *(const s16x8*)(bp5 + ((nt * 16 + kc) << 9));
        acc5[nt] = MFMA_BF16(a, b, acc5[nt]);
      }
    }
    #pragma unroll
    for (int nt = 0; nt < 2; ++nt) {
      int g = nb5 + nt * 16 + ln;                 // gradH column
      int c = (g < 32) ? g + 32 : g - 32;         // out = concat(gradH[:,32:], -gradH[:,:32])
      float s = (g < 32) ? -1.0f : 1.0f;
      #pragma unroll
      for (int r = 0; r < 4; ++r) {
        int grow = row0 + mt5 * 16 + q * 4 + r;
        out[(size_t)grow * 64 + c] = s * acc5[nt][r];
      }
    }
  }
}

extern "C" void kernel_launch(void* const* d_in, const int* in_sizes, int n_in,
                              void* d_out, int out_size, void* d_ws, size_t ws_size,
                              hipStream_t stream) {
  // setup_inputs order: t, x, W0, b0, W1, b1, W2, b2, W3, b3
  const float* x  = (const float*)d_in[1];
  const float* W0 = (const float*)d_in[2];
  const float* b0 = (const float*)d_in[3];
  const float* W1 = (const float*)d_in[4];
  const float* b1 = (const float*)d_in[5];
  const float* W2 = (const float*)d_in[6];
  const float* b2 = (const float*)d_in[7];
  const float* W3 = (const float*)d_in[8];
  u16* ws = (u16*)d_ws;
  float* out = (float*)d_out;

  prep_weights<<<128, 256, 0, stream>>>(W0, W1, W2, ws);
  hnn_fused<<<65536 / M_TILE, 256, 0, stream>>>(x, b0, b1, b2, W3, ws, out);
}

// Round 10
// 227.439 us; speedup vs baseline: 1.8228x; 1.1886x over previous
//
#include <hip/hip_runtime.h>
#include <hip/hip_bf16.h>

typedef unsigned short u16;
typedef short s16x8 __attribute__((ext_vector_type(8)));
typedef float f32x4 __attribute__((ext_vector_type(4)));

#define MFMA_BF16(a, b, c) __builtin_amdgcn_mfma_f32_16x16x32_bf16((a), (b), (c), 0, 0, 0)

static constexpr int D_IN   = 64;
static constexpr int H_DIM  = 512;
static constexpr int M_TILE = 64;
static constexpr int AST    = 520;  // LDS row stride (bf16)
static constexpr int XST    = 72;   // LDS row stride for x tile

__device__ __forceinline__ u16 f2bf(float f) {
  unsigned u = __builtin_bit_cast(unsigned, f);
  u += 0x7fffu + ((u >> 16) & 1u);   // RNE
  return (u16)(u >> 16);
}
__device__ __forceinline__ float bfb2f(unsigned bits16) {
  return __builtin_bit_cast(float, bits16 << 16);
}
__device__ __forceinline__ float fast_tanh(float x) {
  float e = __expf(2.0f * x);
  return 1.0f - 2.0f * __builtin_amdgcn_rcpf(e + 1.0f);
}

// ---- prep: fp32 weights -> bf16, packed in MFMA-B-fragment order ----
// For each (ntg = 16-col tile, kc = 32-wide K chunk): 512 elems stored as
// lane*8 contiguous, lane=(q*16+ln), elem j -> B[k=kc*32+q*8+j][n=ntg*16+ln].
// ws layout (bf16): p0f[64x512] p0b[512x64] p1f p1b p2f p2b  (~2.2MB)
__global__ void prep_weights(const float* __restrict__ W0,
                             const float* __restrict__ W1,
                             const float* __restrict__ W2,
                             u16* __restrict__ ws) {
  u16* p0f = ws;                       // fwd W0: K=64,  N=512
  u16* p0b = p0f + D_IN * H_DIM;       // bwd W0^T: K=512, N=64
  u16* p1f = p0b + D_IN * H_DIM;
  u16* p1b = p1f + H_DIM * H_DIM;
  u16* p2f = p1b + H_DIM * H_DIM;
  u16* p2b = p2f + H_DIM * H_DIM;

  int t = blockIdx.x * 256 + threadIdx.x;   // 32768 threads total
  int lane = t & 63;
  int kc   = (t >> 6) & 15;
  int ntg  = t >> 10;                       // 0..31
  int ln = lane & 15, q = lane >> 4;
  int n = ntg * 16 + ln;
  int k = kc * 32 + q * 8;

  #pragma unroll
  for (int j = 0; j < 8; ++j) {
    p1f[t * 8 + j] = f2bf(W1[(k + j) * 512 + n]);
    p2f[t * 8 + j] = f2bf(W2[(k + j) * 512 + n]);
    p1b[t * 8 + j] = f2bf(W1[n * 512 + (k + j)]);
    p2b[t * 8 + j] = f2bf(W2[n * 512 + (k + j)]);
  }
  if (kc < 2) {  // W0 fwd: K=64 -> kc in {0,1}, ntg 0..31
    int t0 = (ntg * 2 + kc) * 64 + lane;
    #pragma unroll
    for (int j = 0; j < 8; ++j)
      p0f[t0 * 8 + j] = f2bf(W0[(k + j) * 512 + n]);   // W0[k][n], k<64
  }
  if (ntg < 4) { // W0 bwd: N=64 -> ntg 0..3, kc 0..15
    int t0 = (ntg * 16 + kc) * 64 + lane;
    #pragma unroll
    for (int j = 0; j < 8; ++j)
      p0b[t0 * 8 + j] = f2bf(W0[n * 512 + (k + j)]);   // W0[n][k], n<64
  }
}

// Load this wave's 4 B-tiles of k-chunk KC straight into VGPRs (BR[4]).
// Each load = contiguous 1KB per wave (frag-packed). No LDS round-trip.
#define LOAD_B4(BP, KC, BR)                                                     \
  {                                                                             \
    const u16* _sr = (BP) + ((size_t)wave << 15) + ((KC) << 9) + lane * 8;      \
    _Pragma("unroll")                                                           \
    for (int s = 0; s < 4; ++s)                                                 \
      (BR)[s] = *(const s16x8*)(_sr + (s << 13));                               \
  }

// 512-wide GEMM K-loop: wave = 64 rows x 64 cols (4 m-tiles x 4 n-tiles).
// A from LDS buf; B all-register, double-buffered 2-deep (bregA even kc,
// bregB odd kc). Compiler inserts precise vmcnt/lgkmcnt for reg deps.
// Prologue LOAD_B4(BP,0,bregA); LOAD_B4(BP,1,bregB) must run BEFORE entry
// (issued during the preceding epilogue to overlap with VALU).
#define GEMM512_REG(BP)                                                         \
  {                                                                             \
    _Pragma("unroll") for (int mt = 0; mt < 4; ++mt)                            \
      _Pragma("unroll") for (int nt = 0; nt < 4; ++nt)                          \
        acc[mt][nt] = (f32x4){0.f, 0.f, 0.f, 0.f};                              \
    for (int kc2 = 0; kc2 < 8; ++kc2) {                                         \
      const int e = kc2 * 2;                                                    \
      {                                                                         \
        s16x8 a[4];                                                             \
        _Pragma("unroll")                                                       \
        for (int mt = 0; mt < 4; ++mt)                                          \
          a[mt] = *(const s16x8*)(buf + (mt * 16 + ln) * AST + e * 32 + q * 8); \
        _Pragma("unroll")                                                       \
        for (int nt = 0; nt < 4; ++nt)                                          \
          _Pragma("unroll")                                                     \
          for (int mt = 0; mt < 4; ++mt)                                        \
            acc[mt][nt] = MFMA_BF16(a[mt], bregA[nt], acc[mt][nt]);             \
        if (kc2 < 7) LOAD_B4(BP, e + 2, bregA);                                 \
      }                                                                         \
      const int o = e + 1;                                                      \
      {                                                                         \
        s16x8 a[4];                                                             \
        _Pragma("unroll")                                                       \
        for (int mt = 0; mt < 4; ++mt)                                          \
          a[mt] = *(const s16x8*)(buf + (mt * 16 + ln) * AST + o * 32 + q * 8); \
        _Pragma("unroll")                                                       \
        for (int nt = 0; nt < 4; ++nt)                                          \
          _Pragma("unroll")                                                     \
          for (int mt = 0; mt < 4; ++mt)                                        \
            acc[mt][nt] = MFMA_BF16(a[mt], bregB[nt], acc[mt][nt]);             \
        if (kc2 < 7) LOAD_B4(BP, o + 2, bregB);                                 \
      }                                                                         \
    }                                                                           \
  }

// block=512 (8 waves), wave = 64x64 slice. Register budget @(512,2) = 256/wave:
// acc 64 AGPR + h-packs 64 + bregA/B 32 + frags/addr ~40 ~= 200 -> fits, no spill.
// LDS: xs 9K + buf 65K = 74K. M=64 halves per-CU L2 B-traffic vs M=32.
__global__ __launch_bounds__(512, 2) void hnn_fused(
    const float* __restrict__ x,
    const float* __restrict__ bias0,
    const float* __restrict__ bias1,
    const float* __restrict__ bias2,
    const float* __restrict__ W3,
    const u16* __restrict__ ws,
    float* __restrict__ out)
{
  const u16* p0f = ws;
  const u16* p0b = p0f + D_IN * H_DIM;
  const u16* p1f = p0b + D_IN * H_DIM;
  const u16* p1b = p1f + H_DIM * H_DIM;
  const u16* p2f = p1b + H_DIM * H_DIM;
  const u16* p2b = p2f + H_DIM * H_DIM;

  __shared__ __align__(16) u16 xs[M_TILE * XST];    // 9.0 KB
  __shared__ __align__(16) u16 buf[M_TILE * AST];   // 65.0 KB (A activations)

  const int tid  = threadIdx.x;
  const int wave = tid >> 6;      // 0..7
  const int lane = tid & 63;
  const int ln   = lane & 15;
  const int q    = lane >> 4;
  const int nwb  = wave * 64;     // wave's 64-col slice
  const int row0 = blockIdx.x * M_TILE;

  // ---- stage x tile: 64x64 fp32 -> bf16 LDS (512 thr x 8 elems) ----
  {
    int r = tid >> 3, c = (tid & 7) * 8;
    const float4* src = (const float4*)(x + (size_t)(row0 + r) * D_IN + c);
    float4 f0 = src[0];
    float4 f1 = src[1];
    u16* dst = xs + r * XST + c;
    dst[0] = f2bf(f0.x); dst[1] = f2bf(f0.y); dst[2] = f2bf(f0.z); dst[3] = f2bf(f0.w);
    dst[4] = f2bf(f1.x); dst[5] = f2bf(f1.y); dst[6] = f2bf(f1.z); dst[7] = f2bf(f1.w);
  }
  __syncthreads();

  f32x4 acc[4][4];
  s16x8 bregA[4], bregB[4];   // register-B double buffer
  unsigned h0p[4][4][2];      // h0 bf16x2-packed, C-layout (for tanh' in bwd)
  unsigned h1p[4][4][2];
  float bias[4];

  // ================ GEMM0: z0 = x @ W0  (K=64, register-B) ================
  #pragma unroll
  for (int nt = 0; nt < 4; ++nt) bias[nt] = bias0[nwb + nt * 16 + ln];
  #pragma unroll
  for (int mt = 0; mt < 4; ++mt)
    #pragma unroll
    for (int nt = 0; nt < 4; ++nt) acc[mt][nt] = (f32x4){0.f, 0.f, 0.f, 0.f};
  {
    const u16* bpw0 = p0f + (wave << 12) + lane * 8;  // (wave*4 ntg) * 2 kc * 512
    #pragma unroll
    for (int kc = 0; kc < 2; ++kc) {
      s16x8 a[4];
      #pragma unroll
      for (int mt = 0; mt < 4; ++mt)
        a[mt] = *(const s16x8*)(xs + (mt * 16 + ln) * XST + kc * 32 + q * 8);
      #pragma unroll
      for (int nt = 0; nt < 4; ++nt) {
        s16x8 b = *(const s16x8*)(bpw0 + (nt << 10) + (kc << 9));
        #pragma unroll
        for (int mt = 0; mt < 4; ++mt)
          acc[mt][nt] = MFMA_BF16(a[mt], b, acc[mt][nt]);
      }
    }
  }
  LOAD_B4(p1f, 0, bregA);   // prefetch GEMM1 kc 0,1; overlaps epilogue VALU
  LOAD_B4(p1f, 1, bregB);
  // epilogue: h0 = tanh(z0+b0) -> regs + buf (buf first use, no barrier needed)
  #pragma unroll
  for (int mt = 0; mt < 4; ++mt)
    #pragma unroll
    for (int nt = 0; nt < 4; ++nt) {
      int col = nwb + nt * 16 + ln;
      u16 u[4];
      #pragma unroll
      for (int r = 0; r < 4; ++r) {
        float th = fast_tanh(acc[mt][nt][r] + bias[nt]);
        u[r] = f2bf(th);
        buf[(mt * 16 + q * 4 + r) * AST + col] = u[r];
      }
      h0p[mt][nt][0] = (unsigned)u[0] | ((unsigned)u[1] << 16);
      h0p[mt][nt][1] = (unsigned)u[2] | ((unsigned)u[3] << 16);
    }
  __syncthreads();

  // ================ GEMM1: z1 = h0 @ W1 ================
  #pragma unroll
  for (int nt = 0; nt < 4; ++nt) bias[nt] = bias1[nwb + nt * 16 + ln];
  GEMM512_REG(p1f);
  __syncthreads();          // all waves done reading h0 (buf)
  LOAD_B4(p2f, 0, bregA);   // prefetch GEMM2
  LOAD_B4(p2f, 1, bregB);
  #pragma unroll
  for (int mt = 0; mt < 4; ++mt)
    #pragma unroll
    for (int nt = 0; nt < 4; ++nt) {
      int col = nwb + nt * 16 + ln;
      u16 u[4];
      #pragma unroll
      for (int r = 0; r < 4; ++r) {
        float th = fast_tanh(acc[mt][nt][r] + bias[nt]);
        u[r] = f2bf(th);
        buf[(mt * 16 + q * 4 + r) * AST + col] = u[r];
      }
      h1p[mt][nt][0] = (unsigned)u[0] | ((unsigned)u[1] << 16);
      h1p[mt][nt][1] = (unsigned)u[2] | ((unsigned)u[3] << 16);
    }
  __syncthreads();

  // ================ GEMM2: z2 = h1 @ W2 ; gz2 = W3*(1-h2^2) ================
  #pragma unroll
  for (int nt = 0; nt < 4; ++nt) bias[nt] = bias2[nwb + nt * 16 + ln];
  float w3v[4];
  #pragma unroll
  for (int nt = 0; nt < 4; ++nt) w3v[nt] = W3[nwb + nt * 16 + ln];
  GEMM512_REG(p2f);
  __syncthreads();
  LOAD_B4(p2b, 0, bregA);   // prefetch GEMM3
  LOAD_B4(p2b, 1, bregB);
  #pragma unroll
  for (int mt = 0; mt < 4; ++mt)
    #pragma unroll
    for (int nt = 0; nt < 4; ++nt) {
      int col = nwb + nt * 16 + ln;
      #pragma unroll
      for (int r = 0; r < 4; ++r) {
        float th = fast_tanh(acc[mt][nt][r] + bias[nt]);
        float gz = w3v[nt] * (1.0f - th * th);
        buf[(mt * 16 + q * 4 + r) * AST + col] = f2bf(gz);
      }
    }
  __syncthreads();

  // ================ GEMM3: g1 = gz2 @ W2^T ; gz1 = g1*(1-h1^2) ================
  GEMM512_REG(p2b);
  __syncthreads();
  LOAD_B4(p1b, 0, bregA);   // prefetch GEMM4
  LOAD_B4(p1b, 1, bregB);
  #pragma unroll
  for (int mt = 0; mt < 4; ++mt)
    #pragma unroll
    for (int nt = 0; nt < 4; ++nt) {
      int col = nwb + nt * 16 + ln;
      unsigned pa = h1p[mt][nt][0], pb = h1p[mt][nt][1];
      float hh[4] = { bfb2f(pa & 0xffffu), bfb2f(pa >> 16),
                      bfb2f(pb & 0xffffu), bfb2f(pb >> 16) };
      #pragma unroll
      for (int r = 0; r < 4; ++r) {
        float gz = acc[mt][nt][r] * (1.0f - hh[r] * hh[r]);
        buf[(mt * 16 + q * 4 + r) * AST + col] = f2bf(gz);
      }
    }
  __syncthreads();

  // ================ GEMM4: g0 = gz1 @ W1^T ; gz0 = g0*(1-h0^2) ================
  GEMM512_REG(p1b);
  __syncthreads();
  #pragma unroll
  for (int mt = 0; mt < 4; ++mt)
    #pragma unroll
    for (int nt = 0; nt < 4; ++nt) {
      int col = nwb + nt * 16 + ln;
      unsigned pa = h0p[mt][nt][0], pb = h0p[mt][nt][1];
      float hh[4] = { bfb2f(pa & 0xffffu), bfb2f(pa >> 16),
                      bfb2f(pb & 0xffffu), bfb2f(pb >> 16) };
      #pragma unroll
      for (int r = 0; r < 4; ++r) {
        float gz = acc[mt][nt][r] * (1.0f - hh[r] * hh[r]);
        buf[(mt * 16 + q * 4 + r) * AST + col] = f2bf(gz);
      }
    }
  __syncthreads();

  // ================ GEMM5: gradH = gz0 @ W0^T (64x64), symplectic store ======
  // 8 waves x two 16x16 tiles: row tile = wave&3, col half = wave>>2.
  {
    f32x4 acc5[2];
    acc5[0] = (f32x4){0.f, 0.f, 0.f, 0.f};
    acc5[1] = (f32x4){0.f, 0.f, 0.f, 0.f};
    const int mt5 = wave & 3;                  // row tile 0..3
    const int nb5 = (wave >> 2) * 32;          // gradH column base (0 or 32)
    const u16* bp5 = p0b + ((wave >> 2) << 14) + lane * 8;  // ntg5*16kc*512
    #pragma unroll 2
    for (int kc = 0; kc < 16; ++kc) {
      s16x8 a = *(const s16x8*)(buf + (mt5 * 16 + ln) * AST + kc * 32 + q * 8);
      #pragma unroll
      for (int nt = 0; nt < 2; ++nt) {
        s16x8 b = *(const s16x8*)(bp5 + (nt << 13) + (kc << 9));
        acc5[nt] = MFMA_BF16(a, b, acc5[nt]);
      }
    }
    #pragma unroll
    for (int nt = 0; nt < 2; ++nt) {
      int g = nb5 + nt * 16 + ln;                 // gradH column
      int c = (g < 32) ? g + 32 : g - 32;         // out = concat(gradH[:,32:], -gradH[:,:32])
      float s = (g < 32) ? -1.0f : 1.0f;
      #pragma unroll
      for (int r = 0; r < 4; ++r) {
        int grow = row0 + mt5 * 16 + q * 4 + r;
        out[(size_t)grow * 64 + c] = s * acc5[nt][r];
      }
    }
  }
}

extern "C" void kernel_launch(void* const* d_in, const int* in_sizes, int n_in,
                              void* d_out, int out_size, void* d_ws, size_t ws_size,
                              hipStream_t stream) {
  // setup_inputs order: t, x, W0, b0, W1, b1, W2, b2, W3, b3
  const float* x  = (const float*)d_in[1];
  const float* W0 = (const float*)d_in[2];
  const float* b0 = (const float*)d_in[3];
  const float* W1 = (const float*)d_in[4];
  const float* b1 = (const float*)d_in[5];
  const float* W2 = (const float*)d_in[6];
  const float* b2 = (const float*)d_in[7];
  const float* W3 = (const float*)d_in[8];
  u16* ws = (u16*)d_ws;
  float* out = (float*)d_out;

  prep_weights<<<128, 256, 0, stream>>>(W0, W1, W2, ws);
  hnn_fused<<<65536 / M_TILE, 512, 0, stream>>>(x, b0, b1, b2, W3, ws, out);
}